// Round 6
// baseline (789.272 us; speedup 1.0000x reference)
//
#include <hip/hip_runtime.h>
#include <hip/hip_bf16.h>
#include <math.h>

// ---- problem constants ----
static constexpr int LEN = 4096;   // H*W
static constexpr int HN  = 64;     // H
static constexpr int WN  = 64;     // W
static constexpr int NB  = 2;      // batch
static constexpr int DM  = 192;    // d_model
static constexpr int DIM = 384;    // d_inner
static constexpr int NST = 16;     // n_state
static constexpr int DTR = 12;     // dt_rank
static constexpr int KD  = 4;      // directions
static constexpr int NC  = 32;     // scan chunks
static constexpr int CHL = LEN / NC; // 128 elements per chunk

// direction k seq-position -> pixel row index (uniform across a wave)
__device__ __forceinline__ int maprow(int k, int gl) {
    int g = (k & 2) ? (LEN - 1 - gl) : gl;
    return (k & 1) ? (((g & 63) << 6) | (g >> 6)) : g;
}

// ---------------------------------------------------------------------------
// copy x (B,64,L) into F (B,192,L) channels [0,64)
__global__ void k_copy_x(const float* __restrict__ x, float* __restrict__ F) {
    int i = blockIdx.x * 256 + threadIdx.x;          // B*64*L = 524288
    if (i >= NB * 64 * LEN) return;
    int b = i / (64 * LEN); int r = i - b * 64 * LEN;
    F[(size_t)b * DM * LEN + r] = x[i];
}

// ---------------------------------------------------------------------------
// conv3x3 SAME, wave-per-row + shuffle halos. lane = x; block = 4 rows;
// OCPT output channels per thread; optional leaky relu.
template<int OCPT>
__global__ void __launch_bounds__(256) k_conv3s(
    const float* __restrict__ in, int inBufC, int cin,
    const float* __restrict__ w, const float* __restrict__ bias,
    float* __restrict__ out, int outBufC, int co0,
    float slope, int act)
{
    int b  = blockIdx.z;
    int og = blockIdx.y;
    int r  = (blockIdx.x << 2) + (threadIdx.x >> 6);  // spatial row
    int x  = threadIdx.x & 63;                        // lane = column

    float acc[OCPT];
#pragma unroll
    for (int o = 0; o < OCPT; ++o) acc[o] = bias[og * OCPT + o];

    const float* ip0 = in + (size_t)b * inBufC * LEN + r * WN;
    const float* wb  = w + (size_t)(og * OCPT) * cin * 9;
    bool top = (r == 0), bot = (r == HN - 1);
    int xl = (x - 1) & 63, xr = (x + 1) & 63;

#pragma unroll 2
    for (int c = 0; c < cin; ++c) {
        const float* ip = ip0 + (size_t)c * LEN;
        float vm = top ? 0.f : ip[x - WN];
        float v0 = ip[x];
        float vp = bot ? 0.f : ip[x + WN];
        float tml = __shfl(vm, xl), tmr = __shfl(vm, xr);
        float t0l = __shfl(v0, xl), t0r = __shfl(v0, xr);
        float tpl = __shfl(vp, xl), tpr = __shfl(vp, xr);
        float vml = (x == 0) ? 0.f : tml, vmr = (x == 63) ? 0.f : tmr;
        float v0l = (x == 0) ? 0.f : t0l, v0r = (x == 63) ? 0.f : t0r;
        float vpl = (x == 0) ? 0.f : tpl, vpr = (x == 63) ? 0.f : tpr;
        const float* wp = wb + (size_t)c * 9;
#pragma unroll
        for (int o = 0; o < OCPT; ++o) {
            const float* wo = wp + (size_t)o * cin * 9;
            acc[o] += vml * wo[0] + vm * wo[1] + vmr * wo[2]
                    + v0l * wo[3] + v0 * wo[4] + v0r * wo[5]
                    + vpl * wo[6] + vp * wo[7] + vpr * wo[8];
        }
    }
    size_t obase = ((size_t)(b * outBufC + co0 + og * OCPT)) * LEN + r * WN + x;
#pragma unroll
    for (int o = 0; o < OCPT; ++o) {
        float v = acc[o];
        if (act) v = v > 0.f ? v : v * slope;
        out[obase + (size_t)o * LEN] = v;
    }
}

// ---------------------------------------------------------------------------
// LayerNorm over 192 channels of planar F -> xn (B*L, 192) NHWC
__global__ void k_ln(const float* __restrict__ F, const float* __restrict__ g,
                     const float* __restrict__ be, float* __restrict__ xn)
{
    int lane = threadIdx.x & 63;
    int pix  = (blockIdx.x << 2) + (threadIdx.x >> 6);  // B*L pixels, 4 per block
    int b = pix >> 12, l = pix & (LEN - 1);
    const float* fp = F + (size_t)b * DM * LEN + l;
    float v0 = fp[(size_t)lane * LEN];
    float v1 = fp[(size_t)(lane + 64) * LEN];
    float v2 = fp[(size_t)(lane + 128) * LEN];
    float s = v0 + v1 + v2, ss = v0 * v0 + v1 * v1 + v2 * v2;
#pragma unroll
    for (int off = 1; off < 64; off <<= 1) { s += __shfl_xor(s, off); ss += __shfl_xor(ss, off); }
    float mu = s * (1.f / 192.f);
    float var = ss * (1.f / 192.f) - mu * mu;
    float rstd = rsqrtf(var + 1e-5f);
    float* op = xn + (size_t)pix * DM;
    op[lane]       = (v0 - mu) * rstd * g[lane]       + be[lane];
    op[lane + 64]  = (v1 - mu) * rstd * g[lane + 64]  + be[lane + 64];
    op[lane + 128] = (v2 - mu) * rstd * g[lane + 128] + be[lane + 128];
}

// ---------------------------------------------------------------------------
// tiled f32 GEMM: A (B*L, K) NHWC  x  Wt (N, K)  ->  planar (B,outC,L) or NHWC
__global__ void __launch_bounds__(256) k_gemm(
    const float* __restrict__ A, int K,
    const float* __restrict__ Wt,
    const float* __restrict__ res,
    float* __restrict__ Cp, int outC, int nhwc)
{
    __shared__ float As[64][65];
    __shared__ float Bs[64][65];
    int b  = blockIdx.z;
    int l0 = blockIdx.x << 6, n0 = blockIdx.y << 6;
    int tid = threadIdx.x;
    int tl = (tid & 15) << 2, tn = (tid >> 4) << 2;
    float acc[4][4] = {};

    for (int k0 = 0; k0 < K; k0 += 64) {
#pragma unroll
        for (int s = 0; s < 4; ++s) {
            int e = (s << 10) + (tid << 2);
            int row = e >> 6, col = e & 63;
            float4 av = *(const float4*)(A + ((size_t)b * LEN + l0 + row) * K + k0 + col);
            As[row][col] = av.x; As[row][col + 1] = av.y; As[row][col + 2] = av.z; As[row][col + 3] = av.w;
            float4 wv = *(const float4*)(Wt + (size_t)(n0 + row) * K + k0 + col);
            Bs[row][col] = wv.x; Bs[row][col + 1] = wv.y; Bs[row][col + 2] = wv.z; Bs[row][col + 3] = wv.w;
        }
        __syncthreads();
#pragma unroll
        for (int kk = 0; kk < 64; ++kk) {
            float a0 = As[tl][kk], a1 = As[tl + 1][kk], a2 = As[tl + 2][kk], a3 = As[tl + 3][kk];
            float b0 = Bs[tn][kk], b1 = Bs[tn + 1][kk], b2 = Bs[tn + 2][kk], b3 = Bs[tn + 3][kk];
            acc[0][0] += a0 * b0; acc[0][1] += a0 * b1; acc[0][2] += a0 * b2; acc[0][3] += a0 * b3;
            acc[1][0] += a1 * b0; acc[1][1] += a1 * b1; acc[1][2] += a1 * b2; acc[1][3] += a1 * b3;
            acc[2][0] += a2 * b0; acc[2][1] += a2 * b1; acc[2][2] += a2 * b2; acc[2][3] += a2 * b3;
            acc[3][0] += a3 * b0; acc[3][1] += a3 * b1; acc[3][2] += a3 * b2; acc[3][3] += a3 * b3;
        }
        __syncthreads();
    }
    if (!nhwc) {
#pragma unroll
        for (int j = 0; j < 4; ++j) {
            size_t o = ((size_t)(b * outC) + n0 + tn + j) * LEN + l0 + tl;
            float4 v;
            v.x = acc[0][j]; v.y = acc[1][j]; v.z = acc[2][j]; v.w = acc[3][j];
            if (res) {
                float4 r = *(const float4*)(res + o);
                v.x += r.x; v.y += r.y; v.z += r.z; v.w += r.w;
            }
            *(float4*)(Cp + o) = v;
        }
    } else {
#pragma unroll
        for (int i = 0; i < 4; ++i) {
            size_t o = ((size_t)b * LEN + l0 + tl + i) * outC + n0 + tn;
            float4 v;
            v.x = acc[i][0]; v.y = acc[i][1]; v.z = acc[i][2]; v.w = acc[i][3];
            *(float4*)(Cp + o) = v;
        }
    }
}

// ---------------------------------------------------------------------------
// depthwise conv3x3 + SiLU : xp planar (B,384,L) -> unh NHWC (B*L, 384)
__global__ void __launch_bounds__(256) k_dw(
    const float* __restrict__ xp, const float* __restrict__ w,
    const float* __restrict__ bias, float* __restrict__ unh)
{
    __shared__ float t[64][65];
    int b = blockIdx.z, cg = blockIdx.y, r = blockIdx.x;  // r = spatial row
    int x = threadIdx.x & 63, cs = threadIdx.x >> 6;
#pragma unroll
    for (int i = 0; i < 16; ++i) {
        int c = cg * 64 + cs * 16 + i;
        const float* ip = xp + ((size_t)(b * DIM + c)) * LEN;
        const float* wp = w + c * 9;
        float acc = bias[c];
#pragma unroll
        for (int dy = 0; dy < 3; ++dy) {
            int ry = r + dy - 1;
            if ((unsigned)ry >= (unsigned)HN) continue;
#pragma unroll
            for (int dx = 0; dx < 3; ++dx) {
                int xx = x + dx - 1;
                if ((unsigned)xx >= (unsigned)WN) continue;
                acc += ip[ry * WN + xx] * wp[dy * 3 + dx];
            }
        }
        acc = acc / (1.f + __expf(-acc));
        t[x][cs * 16 + i] = acc;
    }
    __syncthreads();
    float* op = unh + ((size_t)b * LEN + r * 64) * DIM + cg * 64;
#pragma unroll
    for (int i = 0; i < 16; ++i) {
        int idx = (i << 8) + threadIdx.x;
        int px = idx >> 6, cc = idx & 63;
        op[(size_t)px * DIM + cc] = t[px][cc];
    }
}

// ---------------------------------------------------------------------------
// fused x_proj + dt GEMV + softplus, NHWC source.
// outputs: bcb (B,4,L,32) coalesced; delta NHWC (B,4,L,384).
__global__ void __launch_bounds__(256) k_xdbl_delta(
    const float* __restrict__ unh, const float* __restrict__ xpw,
    const float* __restrict__ dtw, const float* __restrict__ dtb,
    float* __restrict__ bcb, float* __restrict__ dlt)
{
    __shared__ float xs[64][65];
    __shared__ float ds2[64][65];
    int b = blockIdx.z, k = blockIdx.y;
    int l0 = blockIdx.x << 6;
    int tid = threadIdx.x;
    int lane = tid & 63, wv = tid >> 6;
    const float* ub = unh + (size_t)b * LEN * DIM;
    const float* wp = xpw + (size_t)k * 44 * DIM;
    int c0 = wv * 11;
    float acc[11] = {};

    for (int d0 = 0; d0 < DIM; d0 += 64) {
#pragma unroll
        for (int i = 0; i < 4; ++i) {
            int idx = (i << 8) + tid;                 // 0..1023
            int row = idx >> 4, q = idx & 15;
            int ri = maprow(k, l0 + row);
            float4 v = *(const float4*)(ub + (size_t)ri * DIM + d0 + q * 4);
            xs[row][q * 4] = v.x; xs[row][q * 4 + 1] = v.y;
            xs[row][q * 4 + 2] = v.z; xs[row][q * 4 + 3] = v.w;
        }
        __syncthreads();
#pragma unroll 4
        for (int d = 0; d < 64; ++d) {
            float u = xs[lane][d];
            const float* wd = wp + (size_t)c0 * DIM + d0 + d;
#pragma unroll
            for (int j = 0; j < 11; ++j)
                acc[j] += u * wd[(size_t)j * DIM];
        }
        __syncthreads();
    }

    // park all 44 outputs in LDS: xs[c][l]
#pragma unroll
    for (int j = 0; j < 11; ++j) xs[c0 + j][lane] = acc[j];
    __syncthreads();

    // coalesced B/C store
    float* op = bcb + ((size_t)((b * KD + k) * LEN) + l0) * 32;
#pragma unroll
    for (int i = 0; i < 8; ++i) {
        int idx = (i << 8) + tid;                     // 0..2047
        int l = idx >> 5, cc = idx & 31;
        op[idx] = xs[12 + cc][l];
    }

    // delta NHWC: per 64-d tile, compute into ds2 then coalesced write
    for (int dt = 0; dt < 6; ++dt) {
#pragma unroll
        for (int j = 0; j < 16; ++j) {
            int d = dt * 64 + wv * 16 + j;
            const float* wpd = dtw + ((size_t)(k * DIM + d)) * DTR;
            float s = dtb[k * DIM + d];
#pragma unroll
            for (int r = 0; r < DTR; ++r) s += xs[r][lane] * wpd[r];
            s = (s > 20.f) ? s : __logf(1.f + __expf(s));
            ds2[lane][wv * 16 + j] = s;
        }
        __syncthreads();
        float* dop = dlt + (((size_t)((b * KD + k) * LEN)) + l0) * DIM + dt * 64;
#pragma unroll
        for (int i = 0; i < 16; ++i) {
            int idx = (i << 8) + tid;
            int l = idx >> 6, dd = idx & 63;
            dop[(size_t)l * DIM + dd] = ds2[l][dd];
        }
        __syncthreads();
    }
}

// ---------------------------------------------------------------------------
// chunked scan phase A, NHWC. thread = d; 16 states in registers; B in LDS.
__global__ void __launch_bounds__(384) k_scan_a(
    const float* __restrict__ unh, const float* __restrict__ bcb,
    const float* __restrict__ alog, const float* __restrict__ dlt,
    float* __restrict__ hf, float* __restrict__ pA)
{
    __shared__ float bs[CHL * 16];
    int b = blockIdx.z, k = blockIdx.y, c = blockIdx.x;
    int d = threadIdx.x;
    const float* bc = bcb + ((size_t)((b * KD + k) * LEN) + c * CHL) * 32;
    for (int i = threadIdx.x; i < CHL * 4; i += 384) {
        int l = i >> 2, q = i & 3;
        ((float4*)bs)[i] = ((const float4*)bc)[l * 8 + q];
    }
    __syncthreads();

    float A[16], h[16], p[16];
    const float* ap = alog + ((size_t)(k * DIM + d)) * NST;
#pragma unroll
    for (int q = 0; q < 4; ++q) {
        float4 av = *(const float4*)(ap + q * 4);
        A[q * 4]     = -__expf(av.x); A[q * 4 + 1] = -__expf(av.y);
        A[q * 4 + 2] = -__expf(av.z); A[q * 4 + 3] = -__expf(av.w);
    }
#pragma unroll
    for (int n = 0; n < 16; ++n) { h[n] = 0.f; p[n] = 1.f; }

    const float* dp = dlt + ((size_t)((b * KD + k) * LEN) + c * CHL) * DIM + d;
    const float* ub = unh + (size_t)b * LEN * DIM + d;

    for (int l0 = 0; l0 < CHL; l0 += 4) {
        float dv[4], uu[4];
#pragma unroll
        for (int j = 0; j < 4; ++j) {
            int gl = c * CHL + l0 + j;
            dv[j] = dp[(size_t)(l0 + j) * DIM];
            uu[j] = ub[(size_t)maprow(k, gl) * DIM];
        }
#pragma unroll
        for (int j = 0; j < 4; ++j) {
            float du = dv[j] * uu[j];
            const float* bl = bs + (l0 + j) * 16;
#pragma unroll
            for (int n = 0; n < 16; ++n) {
                float dA = __expf(dv[j] * A[n]);
                h[n] = dA * h[n] + du * bl[n];
                p[n] *= dA;
            }
        }
    }
    size_t s0 = (((size_t)((b * KD + k) * DIM) + d) * NST) * NC + c;
#pragma unroll
    for (int n = 0; n < 16; ++n) { hf[s0 + (size_t)n * NC] = h[n]; pA[s0 + (size_t)n * NC] = p[n]; }
}

// phase B: serial carry combine over chunks; hf[c] overwritten with carry-IN.
__global__ void k_scan_b(float* __restrict__ hf, const float* __restrict__ pA)
{
    int s = blockIdx.x * 256 + threadIdx.x;          // 49152 states
    float* hp = hf + (size_t)s * NC;
    const float* pp = pA + (size_t)s * NC;
    float car = 0.f;
#pragma unroll
    for (int c = 0; c < NC; ++c) {
        float hfc = hp[c], pc = pp[c];
        hp[c] = car;
        car = pc * car + hfc;
    }
}

// phase C: re-run chunk from carry-in; y in-register; software-pipelined loads.
__global__ void __launch_bounds__(384) k_scan_c(
    const float* __restrict__ unh, const float* __restrict__ bcb,
    const float* __restrict__ alog, const float* __restrict__ hf,
    float* __restrict__ dlt)
{
    __shared__ float bs[CHL * 32];
    int b = blockIdx.z, k = blockIdx.y, c = blockIdx.x;
    int d = threadIdx.x;
    const float* bc = bcb + ((size_t)((b * KD + k) * LEN) + c * CHL) * 32;
    for (int i = threadIdx.x; i < CHL * 8; i += 384)
        ((float4*)bs)[i] = ((const float4*)bc)[i];
    __syncthreads();

    float A[16], h[16];
    const float* ap = alog + ((size_t)(k * DIM + d)) * NST;
#pragma unroll
    for (int q = 0; q < 4; ++q) {
        float4 av = *(const float4*)(ap + q * 4);
        A[q * 4]     = -__expf(av.x); A[q * 4 + 1] = -__expf(av.y);
        A[q * 4 + 2] = -__expf(av.z); A[q * 4 + 3] = -__expf(av.w);
    }
    size_t s0 = (((size_t)((b * KD + k) * DIM) + d) * NST) * NC + c;
#pragma unroll
    for (int n = 0; n < 16; ++n) h[n] = hf[s0 + (size_t)n * NC];

    float* dp = dlt + ((size_t)((b * KD + k) * LEN) + c * CHL) * DIM + d;
    const float* ub = unh + (size_t)b * LEN * DIM + d;

    float dv0[4], uu0[4], dv1[4], uu1[4];
#pragma unroll
    for (int j = 0; j < 4; ++j) {
        int gl = c * CHL + j;
        dv0[j] = dp[(size_t)j * DIM];
        uu0[j] = ub[(size_t)maprow(k, gl) * DIM];
    }
    for (int l0 = 0; l0 < CHL; l0 += 4) {
        if (l0 + 4 < CHL) {
#pragma unroll
            for (int j = 0; j < 4; ++j) {
                int gl = c * CHL + l0 + 4 + j;
                dv1[j] = dp[(size_t)(l0 + 4 + j) * DIM];
                uu1[j] = ub[(size_t)maprow(k, gl) * DIM];
            }
        }
        float ys[4];
#pragma unroll
        for (int j = 0; j < 4; ++j) {
            const float* bl = bs + (l0 + j) * 32;
            float du = dv0[j] * uu0[j];
            float y = 0.f;
#pragma unroll
            for (int n = 0; n < 16; ++n) {
                float dA = __expf(dv0[j] * A[n]);
                h[n] = dA * h[n] + du * bl[n];
                y += h[n] * bl[16 + n];
            }
            ys[j] = y;
        }
#pragma unroll
        for (int j = 0; j < 4; ++j) dp[(size_t)(l0 + j) * DIM] = ys[j];
#pragma unroll
        for (int j = 0; j < 4; ++j) { dv0[j] = dv1[j]; uu0[j] = uu1[j]; }
    }
}

// ---------------------------------------------------------------------------
// merge 4 directions + D*u + out-LN + silu(z) gate -> yg (B*L, 384) NHWC
__global__ void k_merge(const float* __restrict__ y4, const float* __restrict__ unh,
                        const float* __restrict__ Ds, const float* __restrict__ ong,
                        const float* __restrict__ onb, const float* __restrict__ zt,
                        float* __restrict__ yg)
{
    int lane = threadIdx.x & 63;
    int pix = (blockIdx.x << 2) + (threadIdx.x >> 6);
    int b = pix >> 12, l = pix & (LEN - 1);
    int hh = l >> 6, ww = l & 63;
    int lt = (ww << 6) + hh;
    const float* y0p = y4 + ((size_t)((b * KD + 0) * LEN) + l) * DIM;
    const float* y1p = y4 + ((size_t)((b * KD + 1) * LEN) + lt) * DIM;
    const float* y2p = y4 + ((size_t)((b * KD + 2) * LEN) + (LEN - 1 - l)) * DIM;
    const float* y3p = y4 + ((size_t)((b * KD + 3) * LEN) + (LEN - 1 - lt)) * DIM;
    const float* up  = unh + ((size_t)b * LEN + l) * DIM;
    float v[6]; float s = 0.f, ss = 0.f;
#pragma unroll
    for (int j = 0; j < 6; ++j) {
        int d = lane + (j << 6);
        float y = y0p[d] + y1p[d] + y2p[d] + y3p[d];
        float dsum = Ds[d] + Ds[DIM + d] + Ds[2 * DIM + d] + Ds[3 * DIM + d];
        y += dsum * up[d];
        v[j] = y; s += y; ss += y * y;
    }
#pragma unroll
    for (int off = 1; off < 64; off <<= 1) { s += __shfl_xor(s, off); ss += __shfl_xor(ss, off); }
    float mu = s * (1.f / 384.f);
    float var = ss * (1.f / 384.f) - mu * mu;
    float rstd = rsqrtf(var + 1e-5f);
    const float* zp = zt + (size_t)pix * DIM;
    float* op = yg + (size_t)pix * DIM;
#pragma unroll
    for (int j = 0; j < 6; ++j) {
        int d = lane + (j << 6);
        float zz = zp[d];
        float gate = zz / (1.f + __expf(-zz));
        op[d] = ((v[j] - mu) * rstd * ong[d] + onb[d]) * gate;
    }
}

// ---------------------------------------------------------------------------
extern "C" void kernel_launch(void* const* d_in, const int* in_sizes, int n_in,
                              void* d_out, int out_size, void* d_ws, size_t ws_size,
                              hipStream_t stream)
{
    const float* x    = (const float*)d_in[0];
    const float* c1w  = (const float*)d_in[1];  const float* c1b = (const float*)d_in[2];
    const float* c2w  = (const float*)d_in[3];  const float* c2b = (const float*)d_in[4];
    const float* c3w  = (const float*)d_in[5];  const float* c3b = (const float*)d_in[6];
    const float* c4w  = (const float*)d_in[7];  const float* c4b = (const float*)d_in[8];
    const float* c5w  = (const float*)d_in[9];  const float* c5b = (const float*)d_in[10];
    const float* ln1g = (const float*)d_in[11]; const float* ln1b= (const float*)d_in[12];
    const float* ipw  = (const float*)d_in[13];
    const float* dww  = (const float*)d_in[14]; const float* dwb = (const float*)d_in[15];
    const float* xpw  = (const float*)d_in[16];
    const float* dtw  = (const float*)d_in[17]; const float* dtb = (const float*)d_in[18];
    const float* alog = (const float*)d_in[19]; const float* dsv = (const float*)d_in[20];
    const float* ong  = (const float*)d_in[21]; const float* onb = (const float*)d_in[22];
    const float* opw  = (const float*)d_in[23];
    float* out = (float*)d_out;

    float* ws   = (float*)d_ws;
    float* F    = ws;                   // (B,192,L) planar       1,572,864
    float* XN   = F    + 1572864;       // (B*L,192); HF in scan; later sa planar
    float* XP   = XN   + 1572864;       // (B,384,L) planar xp    3,145,728 (PA alias)
    float* ZT   = XP   + 3145728;       // (B*L,384) z NHWC       3,145,728
    float* XCNH = ZT   + 3145728;       // (B*L,384) u NHWC       3,145,728
    float* BCB  = XCNH + 3145728;       // (B,4,L,32)             1,048,576
    float* DLT  = BCB  + 1048576;       // (B,4,L,384) delta->y   12,582,912
    float* YG   = DLT  + 12582912;      // (B*L,384) merge out    3,145,728
    // total 28,311,552 floats = 108 MB
    float* HF = XN;                     // 1,572,864 = NB*KD*DIM*NST*NC exactly
    float* PA = XP;                     // first 1,572,864 of XP (dead after k_dw)

    // stage A: dense conv block (wave-per-row shuffle conv)
    k_copy_x<<<dim3(2048), 256, 0, stream>>>(x, F);
    k_conv3s<2><<<dim3(16, 16, NB), 256, 0, stream>>>(F, DM, 64,  c1w, c1b, F, DM, 64,  0.01f, 1);
    k_conv3s<2><<<dim3(16, 16, NB), 256, 0, stream>>>(F, DM, 96,  c2w, c2b, F, DM, 96,  0.01f, 1);
    k_conv3s<2><<<dim3(16, 16, NB), 256, 0, stream>>>(F, DM, 128, c3w, c3b, F, DM, 128, 0.01f, 1);
    k_conv3s<2><<<dim3(16, 16, NB), 256, 0, stream>>>(F, DM, 160, c4w, c4b, F, DM, 160, 0.01f, 1);

    // stage B: VSS block
    k_ln<<<dim3(NB * LEN / 4), 256, 0, stream>>>(F, ln1g, ln1b, XN);
    k_gemm<<<dim3(LEN / 64, DIM / 64, NB), 256, 0, stream>>>(XN, DM, ipw, nullptr, XP, DIM, 0);
    k_gemm<<<dim3(LEN / 64, DIM / 64, NB), 256, 0, stream>>>(XN, DM, ipw + (size_t)DIM * DM, nullptr, ZT, DIM, 1);
    k_dw<<<dim3(HN, DIM / 64, NB), 256, 0, stream>>>(XP, dww, dwb, XCNH);
    k_xdbl_delta<<<dim3(LEN / 64, KD, NB), 256, 0, stream>>>(XCNH, xpw, dtw, dtb, BCB, DLT);
    k_scan_a<<<dim3(NC, KD, NB), 384, 0, stream>>>(XCNH, BCB, alog, DLT, HF, PA);
    k_scan_b<<<dim3(NB * KD * DIM * NST / 256), 256, 0, stream>>>(HF, PA);
    k_scan_c<<<dim3(NC, KD, NB), 384, 0, stream>>>(XCNH, BCB, alog, HF, DLT);
    k_merge<<<dim3(NB * LEN / 4), 256, 0, stream>>>(DLT, XCNH, dsv, ong, onb, ZT, YG);
    k_gemm<<<dim3(LEN / 64, DM / 64, NB), 256, 0, stream>>>(YG, DIM, opw, F, XN, DM, 0);

    // stage C: final conv
    k_conv3s<4><<<dim3(16, 16, NB), 256, 0, stream>>>(XN, DM, DM, c5w, c5b, out, 64, 0, 0.f, 0);
}

// Round 7
// 558.855 us; speedup vs baseline: 1.4123x; 1.4123x over previous
//
#include <hip/hip_runtime.h>
#include <hip/hip_bf16.h>
#include <math.h>

// ---- problem constants ----
static constexpr int LEN = 4096;   // H*W
static constexpr int HN  = 64;     // H
static constexpr int WN  = 64;     // W
static constexpr int NB  = 2;      // batch
static constexpr int DM  = 192;    // d_model
static constexpr int DIM = 384;    // d_inner
static constexpr int NST = 16;     // n_state
static constexpr int DTR = 12;     // dt_rank
static constexpr int KD  = 4;      // directions
static constexpr int NC  = 32;     // scan chunks
static constexpr int CHL = LEN / NC; // 128 elements per chunk

// direction k seq-position -> pixel row index (uniform across a wave)
__device__ __forceinline__ int maprow(int k, int gl) {
    int g = (k & 2) ? (LEN - 1 - gl) : gl;
    return (k & 1) ? (((g & 63) << 6) | (g >> 6)) : g;
}

// ---------------------------------------------------------------------------
// weight transform: w (co,ci,3,3) -> wt (t, ci, co)
__global__ void k_wtr(const float* __restrict__ w, float* __restrict__ wt,
                      int cin, int cout, int n)
{
    int idx = blockIdx.x * 256 + threadIdx.x;
    if (idx >= n) return;
    int co = idx % cout; int r = idx / cout;
    int ci = r % cin; int t = r / cin;
    wt[idx] = w[((size_t)(co * cin + ci)) * 9 + t];
}

// ---------------------------------------------------------------------------
// x (B,64,L) planar -> FN NHWC cols [0,64)
__global__ void k_tr_in(const float* __restrict__ x, float* __restrict__ FN)
{
    __shared__ float t[64][65];
    int b = blockIdx.y, r = blockIdx.x;
    int tid = threadIdx.x;
#pragma unroll
    for (int i = 0; i < 16; ++i) {
        int idx = (i << 8) + tid;
        int c = idx >> 6, xc = idx & 63;
        t[c][xc] = x[((size_t)(b * 64 + c)) * LEN + r * WN + xc];
    }
    __syncthreads();
#pragma unroll
    for (int i = 0; i < 16; ++i) {
        int idx = (i << 8) + tid;
        int px = idx >> 6, c = idx & 63;
        FN[((size_t)(b * LEN + r * WN + px)) * DM + c] = t[c][px];
    }
}

// ---------------------------------------------------------------------------
// implicit-GEMM conv3x3, dy-split partials. tile 64px x 32oc, KC=32 ci.
// blockIdx: x = spatial row y0 (64), y = oc block, z = b*3 + s (s=dy).
// PLANAR=0: partials (s,b,L,32); PLANAR=1: partials (s,b,64,L).
template<int PLANAR>
__global__ void __launch_bounds__(256) k_convg(
    const float* __restrict__ in, int cbuf, int cin,
    const float* __restrict__ wt, int wstride,
    float* __restrict__ part)
{
    __shared__ float As[64][36];
    __shared__ float Bs[32][36];
    int zz = blockIdx.z;
    int b = zz / 3, s = zz % 3;
    int y0 = blockIdx.x;
    int n0 = blockIdx.y << 5;
    int tid = threadIdx.x;
    int tl = tid & 15, tn = (tid >> 4) << 1;
    int y = y0 + s - 1;
    bool yok = (unsigned)y < (unsigned)HN;
    const float* inb = in + ((size_t)b * LEN + (size_t)y * WN) * cbuf;
    float acc[4][2] = {};

    int nchunk = 3 * (cin >> 5);
    for (int cc = 0; cc < nchunk; ++cc) {
        int dx = cc % 3;
        int ci0 = (cc / 3) << 5;
        // stage As[px][ci'] (64x32), float4 over ci
#pragma unroll
        for (int it = 0; it < 2; ++it) {
            int fi = (it << 8) + tid;          // 0..511
            int px = fi >> 3, ci4 = (fi & 7) << 2;
            int xx = px + dx - 1;
            float4 v = make_float4(0.f, 0.f, 0.f, 0.f);
            if (yok && (unsigned)xx < (unsigned)WN)
                v = *(const float4*)(inb + (size_t)xx * cbuf + ci0 + ci4);
            *(float4*)(&As[px][ci4]) = v;
        }
        // stage Bs[ci'][oc] (32x32)
        {
            int fi = tid << 2;                 // 0..1023
            int ci = fi >> 5, oc = fi & 31;
            int t = s * 3 + dx;
            float4 wv = *(const float4*)(wt + (size_t)(t * cin + ci0 + ci) * wstride + n0 + oc);
            *(float4*)(&Bs[ci][oc]) = wv;
        }
        __syncthreads();
#pragma unroll 8
        for (int k = 0; k < 32; ++k) {
            float b0 = Bs[k][tn], b1 = Bs[k][tn + 1];
#pragma unroll
            for (int i = 0; i < 4; ++i) {
                float a = As[tl + (i << 4)][k];
                acc[i][0] += a * b0;
                acc[i][1] += a * b1;
            }
        }
        __syncthreads();
    }
    if (PLANAR) {
#pragma unroll
        for (int j = 0; j < 2; ++j) {
            float* pp = part + ((size_t)((s * NB + b) * 64 + n0 + tn + j)) * LEN + y0 * WN + tl;
#pragma unroll
            for (int i = 0; i < 4; ++i) pp[i << 4] = acc[i][j];
        }
    } else {
#pragma unroll
        for (int i = 0; i < 4; ++i) {
            float* pp = part + (((size_t)(s * NB + b) * LEN) + y0 * WN + tl + (i << 4)) * 32 + tn;
            pp[0] = acc[i][0]; pp[1] = acc[i][1];
        }
    }
}

// epilogue: sum 3 dy-partials + bias + leakyrelu -> FN NHWC col block
__global__ void k_ep_nhwc(const float* __restrict__ part, const float* __restrict__ bias,
                          float* __restrict__ FN, int co0, float slope)
{
    int idx = blockIdx.x * 256 + threadIdx.x;   // B*L*32
    int co = idx & 31, px = idx >> 5;
    const size_t S = (size_t)NB * LEN * 32;
    float v = part[idx] + part[S + idx] + part[2 * S + idx] + bias[co];
    v = v > 0.f ? v : v * slope;
    FN[(size_t)px * DM + co0 + co] = v;
}

// epilogue: sum 3 dy-partials + bias -> planar out (B,64,L)
__global__ void k_ep_pl(const float* __restrict__ part, const float* __restrict__ bias,
                        float* __restrict__ out)
{
    int idx = blockIdx.x * 256 + threadIdx.x;   // B*64*LEN
    int oc = (idx >> 12) & 63;
    const size_t S = (size_t)NB * 64 * LEN;
    float v = part[idx] + part[S + idx] + part[2 * S + idx] + bias[oc];
    out[idx] = v;
}

// ---------------------------------------------------------------------------
// LayerNorm over 192 channels, NHWC in/out
__global__ void k_ln(const float* __restrict__ FN, const float* __restrict__ g,
                     const float* __restrict__ be, float* __restrict__ xn)
{
    int lane = threadIdx.x & 63;
    int pix  = (blockIdx.x << 2) + (threadIdx.x >> 6);
    const float* fp = FN + (size_t)pix * DM;
    float v0 = fp[lane];
    float v1 = fp[lane + 64];
    float v2 = fp[lane + 128];
    float s = v0 + v1 + v2, ss = v0 * v0 + v1 * v1 + v2 * v2;
#pragma unroll
    for (int off = 1; off < 64; off <<= 1) { s += __shfl_xor(s, off); ss += __shfl_xor(ss, off); }
    float mu = s * (1.f / 192.f);
    float var = ss * (1.f / 192.f) - mu * mu;
    float rstd = rsqrtf(var + 1e-5f);
    float* op = xn + (size_t)pix * DM;
    op[lane]       = (v0 - mu) * rstd * g[lane]       + be[lane];
    op[lane + 64]  = (v1 - mu) * rstd * g[lane + 64]  + be[lane + 64];
    op[lane + 128] = (v2 - mu) * rstd * g[lane + 128] + be[lane + 128];
}

// ---------------------------------------------------------------------------
// tiled f32 GEMM: A (B*L, K) NHWC x Wt (N, K) -> planar (B,outC,L) or NHWC.
// res added in either layout (same addressing as the store).
__global__ void __launch_bounds__(256) k_gemm(
    const float* __restrict__ A, int K,
    const float* __restrict__ Wt,
    const float* __restrict__ res,
    float* __restrict__ Cp, int outC, int nhwc)
{
    __shared__ float As[64][65];
    __shared__ float Bs[64][65];
    int b  = blockIdx.z;
    int l0 = blockIdx.x << 6, n0 = blockIdx.y << 6;
    int tid = threadIdx.x;
    int tl = (tid & 15) << 2, tn = (tid >> 4) << 2;
    float acc[4][4] = {};

    for (int k0 = 0; k0 < K; k0 += 64) {
#pragma unroll
        for (int s = 0; s < 4; ++s) {
            int e = (s << 10) + (tid << 2);
            int row = e >> 6, col = e & 63;
            float4 av = *(const float4*)(A + ((size_t)b * LEN + l0 + row) * K + k0 + col);
            As[row][col] = av.x; As[row][col + 1] = av.y; As[row][col + 2] = av.z; As[row][col + 3] = av.w;
            float4 wv = *(const float4*)(Wt + (size_t)(n0 + row) * K + k0 + col);
            Bs[row][col] = wv.x; Bs[row][col + 1] = wv.y; Bs[row][col + 2] = wv.z; Bs[row][col + 3] = wv.w;
        }
        __syncthreads();
#pragma unroll
        for (int kk = 0; kk < 64; ++kk) {
            float a0 = As[tl][kk], a1 = As[tl + 1][kk], a2 = As[tl + 2][kk], a3 = As[tl + 3][kk];
            float b0 = Bs[tn][kk], b1 = Bs[tn + 1][kk], b2 = Bs[tn + 2][kk], b3 = Bs[tn + 3][kk];
            acc[0][0] += a0 * b0; acc[0][1] += a0 * b1; acc[0][2] += a0 * b2; acc[0][3] += a0 * b3;
            acc[1][0] += a1 * b0; acc[1][1] += a1 * b1; acc[1][2] += a1 * b2; acc[1][3] += a1 * b3;
            acc[2][0] += a2 * b0; acc[2][1] += a2 * b1; acc[2][2] += a2 * b2; acc[2][3] += a2 * b3;
            acc[3][0] += a3 * b0; acc[3][1] += a3 * b1; acc[3][2] += a3 * b2; acc[3][3] += a3 * b3;
        }
        __syncthreads();
    }
    if (!nhwc) {
#pragma unroll
        for (int j = 0; j < 4; ++j) {
            size_t o = ((size_t)(b * outC) + n0 + tn + j) * LEN + l0 + tl;
            float4 v;
            v.x = acc[0][j]; v.y = acc[1][j]; v.z = acc[2][j]; v.w = acc[3][j];
            if (res) {
                float4 r = *(const float4*)(res + o);
                v.x += r.x; v.y += r.y; v.z += r.z; v.w += r.w;
            }
            *(float4*)(Cp + o) = v;
        }
    } else {
#pragma unroll
        for (int i = 0; i < 4; ++i) {
            size_t o = ((size_t)b * LEN + l0 + tl + i) * outC + n0 + tn;
            float4 v;
            v.x = acc[i][0]; v.y = acc[i][1]; v.z = acc[i][2]; v.w = acc[i][3];
            if (res) {
                float4 r = *(const float4*)(res + o);
                v.x += r.x; v.y += r.y; v.z += r.z; v.w += r.w;
            }
            *(float4*)(Cp + o) = v;
        }
    }
}

// ---------------------------------------------------------------------------
// depthwise conv3x3 + SiLU : xp planar (B,384,L) -> unh NHWC (B*L, 384)
__global__ void __launch_bounds__(256) k_dw(
    const float* __restrict__ xp, const float* __restrict__ w,
    const float* __restrict__ bias, float* __restrict__ unh)
{
    __shared__ float t[64][65];
    int b = blockIdx.z, cg = blockIdx.y, r = blockIdx.x;  // r = spatial row
    int x = threadIdx.x & 63, cs = threadIdx.x >> 6;
#pragma unroll
    for (int i = 0; i < 16; ++i) {
        int c = cg * 64 + cs * 16 + i;
        const float* ip = xp + ((size_t)(b * DIM + c)) * LEN;
        const float* wp = w + c * 9;
        float acc = bias[c];
#pragma unroll
        for (int dy = 0; dy < 3; ++dy) {
            int ry = r + dy - 1;
            if ((unsigned)ry >= (unsigned)HN) continue;
#pragma unroll
            for (int dx = 0; dx < 3; ++dx) {
                int xx = x + dx - 1;
                if ((unsigned)xx >= (unsigned)WN) continue;
                acc += ip[ry * WN + xx] * wp[dy * 3 + dx];
            }
        }
        acc = acc / (1.f + __expf(-acc));
        t[x][cs * 16 + i] = acc;
    }
    __syncthreads();
    float* op = unh + ((size_t)b * LEN + r * 64) * DIM + cg * 64;
#pragma unroll
    for (int i = 0; i < 16; ++i) {
        int idx = (i << 8) + threadIdx.x;
        int px = idx >> 6, cc = idx & 63;
        op[(size_t)px * DIM + cc] = t[px][cc];
    }
}

// ---------------------------------------------------------------------------
// fused x_proj + dt GEMV + softplus, NHWC source.
__global__ void __launch_bounds__(256) k_xdbl_delta(
    const float* __restrict__ unh, const float* __restrict__ xpw,
    const float* __restrict__ dtw, const float* __restrict__ dtb,
    float* __restrict__ bcb, float* __restrict__ dlt)
{
    __shared__ float xs[64][65];
    __shared__ float ds2[64][65];
    int b = blockIdx.z, k = blockIdx.y;
    int l0 = blockIdx.x << 6;
    int tid = threadIdx.x;
    int lane = tid & 63, wv = tid >> 6;
    const float* ub = unh + (size_t)b * LEN * DIM;
    const float* wp = xpw + (size_t)k * 44 * DIM;
    int c0 = wv * 11;
    float acc[11] = {};

    for (int d0 = 0; d0 < DIM; d0 += 64) {
#pragma unroll
        for (int i = 0; i < 4; ++i) {
            int idx = (i << 8) + tid;
            int row = idx >> 4, q = idx & 15;
            int ri = maprow(k, l0 + row);
            float4 v = *(const float4*)(ub + (size_t)ri * DIM + d0 + q * 4);
            xs[row][q * 4] = v.x; xs[row][q * 4 + 1] = v.y;
            xs[row][q * 4 + 2] = v.z; xs[row][q * 4 + 3] = v.w;
        }
        __syncthreads();
#pragma unroll 4
        for (int d = 0; d < 64; ++d) {
            float u = xs[lane][d];
            const float* wd = wp + (size_t)c0 * DIM + d0 + d;
#pragma unroll
            for (int j = 0; j < 11; ++j)
                acc[j] += u * wd[(size_t)j * DIM];
        }
        __syncthreads();
    }

#pragma unroll
    for (int j = 0; j < 11; ++j) xs[c0 + j][lane] = acc[j];
    __syncthreads();

    float* op = bcb + ((size_t)((b * KD + k) * LEN) + l0) * 32;
#pragma unroll
    for (int i = 0; i < 8; ++i) {
        int idx = (i << 8) + tid;
        int l = idx >> 5, cc = idx & 31;
        op[idx] = xs[12 + cc][l];
    }

    for (int dt = 0; dt < 6; ++dt) {
#pragma unroll
        for (int j = 0; j < 16; ++j) {
            int d = dt * 64 + wv * 16 + j;
            const float* wpd = dtw + ((size_t)(k * DIM + d)) * DTR;
            float s = dtb[k * DIM + d];
#pragma unroll
            for (int r = 0; r < DTR; ++r) s += xs[r][lane] * wpd[r];
            s = (s > 20.f) ? s : __logf(1.f + __expf(s));
            ds2[lane][wv * 16 + j] = s;
        }
        __syncthreads();
        float* dop = dlt + (((size_t)((b * KD + k) * LEN)) + l0) * DIM + dt * 64;
#pragma unroll
        for (int i = 0; i < 16; ++i) {
            int idx = (i << 8) + tid;
            int l = idx >> 6, dd = idx & 63;
            dop[(size_t)l * DIM + dd] = ds2[l][dd];
        }
        __syncthreads();
    }
}

// ---------------------------------------------------------------------------
// chunked scan phase A, NHWC. thread = d; 16 states in registers; B in LDS.
__global__ void __launch_bounds__(384) k_scan_a(
    const float* __restrict__ unh, const float* __restrict__ bcb,
    const float* __restrict__ alog, const float* __restrict__ dlt,
    float* __restrict__ hf, float* __restrict__ pA)
{
    __shared__ float bs[CHL * 16];
    int b = blockIdx.z, k = blockIdx.y, c = blockIdx.x;
    int d = threadIdx.x;
    const float* bc = bcb + ((size_t)((b * KD + k) * LEN) + c * CHL) * 32;
    for (int i = threadIdx.x; i < CHL * 4; i += 384) {
        int l = i >> 2, q = i & 3;
        ((float4*)bs)[i] = ((const float4*)bc)[l * 8 + q];
    }
    __syncthreads();

    float A[16], h[16], p[16];
    const float* ap = alog + ((size_t)(k * DIM + d)) * NST;
#pragma unroll
    for (int q = 0; q < 4; ++q) {
        float4 av = *(const float4*)(ap + q * 4);
        A[q * 4]     = -__expf(av.x); A[q * 4 + 1] = -__expf(av.y);
        A[q * 4 + 2] = -__expf(av.z); A[q * 4 + 3] = -__expf(av.w);
    }
#pragma unroll
    for (int n = 0; n < 16; ++n) { h[n] = 0.f; p[n] = 1.f; }

    const float* dp = dlt + ((size_t)((b * KD + k) * LEN) + c * CHL) * DIM + d;
    const float* ub = unh + (size_t)b * LEN * DIM + d;

    for (int l0 = 0; l0 < CHL; l0 += 4) {
        float dv[4], uu[4];
#pragma unroll
        for (int j = 0; j < 4; ++j) {
            int gl = c * CHL + l0 + j;
            dv[j] = dp[(size_t)(l0 + j) * DIM];
            uu[j] = ub[(size_t)maprow(k, gl) * DIM];
        }
#pragma unroll
        for (int j = 0; j < 4; ++j) {
            float du = dv[j] * uu[j];
            const float* bl = bs + (l0 + j) * 16;
#pragma unroll
            for (int n = 0; n < 16; ++n) {
                float dA = __expf(dv[j] * A[n]);
                h[n] = dA * h[n] + du * bl[n];
                p[n] *= dA;
            }
        }
    }
    size_t s0 = (((size_t)((b * KD + k) * DIM) + d) * NST) * NC + c;
#pragma unroll
    for (int n = 0; n < 16; ++n) { hf[s0 + (size_t)n * NC] = h[n]; pA[s0 + (size_t)n * NC] = p[n]; }
}

// phase B: serial carry combine over chunks; hf[c] overwritten with carry-IN.
__global__ void k_scan_b(float* __restrict__ hf, const float* __restrict__ pA)
{
    int s = blockIdx.x * 256 + threadIdx.x;
    float* hp = hf + (size_t)s * NC;
    const float* pp = pA + (size_t)s * NC;
    float car = 0.f;
#pragma unroll
    for (int c = 0; c < NC; ++c) {
        float hfc = hp[c], pc = pp[c];
        hp[c] = car;
        car = pc * car + hfc;
    }
}

// phase C: re-run chunk from carry-in; y in-register; software-pipelined loads.
__global__ void __launch_bounds__(384) k_scan_c(
    const float* __restrict__ unh, const float* __restrict__ bcb,
    const float* __restrict__ alog, const float* __restrict__ hf,
    float* __restrict__ dlt)
{
    __shared__ float bs[CHL * 32];
    int b = blockIdx.z, k = blockIdx.y, c = blockIdx.x;
    int d = threadIdx.x;
    const float* bc = bcb + ((size_t)((b * KD + k) * LEN) + c * CHL) * 32;
    for (int i = threadIdx.x; i < CHL * 8; i += 384)
        ((float4*)bs)[i] = ((const float4*)bc)[i];
    __syncthreads();

    float A[16], h[16];
    const float* ap = alog + ((size_t)(k * DIM + d)) * NST;
#pragma unroll
    for (int q = 0; q < 4; ++q) {
        float4 av = *(const float4*)(ap + q * 4);
        A[q * 4]     = -__expf(av.x); A[q * 4 + 1] = -__expf(av.y);
        A[q * 4 + 2] = -__expf(av.z); A[q * 4 + 3] = -__expf(av.w);
    }
    size_t s0 = (((size_t)((b * KD + k) * DIM) + d) * NST) * NC + c;
#pragma unroll
    for (int n = 0; n < 16; ++n) h[n] = hf[s0 + (size_t)n * NC];

    float* dp = dlt + ((size_t)((b * KD + k) * LEN) + c * CHL) * DIM + d;
    const float* ub = unh + (size_t)b * LEN * DIM + d;

    float dv0[4], uu0[4], dv1[4], uu1[4];
#pragma unroll
    for (int j = 0; j < 4; ++j) {
        int gl = c * CHL + j;
        dv0[j] = dp[(size_t)j * DIM];
        uu0[j] = ub[(size_t)maprow(k, gl) * DIM];
    }
    for (int l0 = 0; l0 < CHL; l0 += 4) {
        if (l0 + 4 < CHL) {
#pragma unroll
            for (int j = 0; j < 4; ++j) {
                int gl = c * CHL + l0 + 4 + j;
                dv1[j] = dp[(size_t)(l0 + 4 + j) * DIM];
                uu1[j] = ub[(size_t)maprow(k, gl) * DIM];
            }
        }
        float ys[4];
#pragma unroll
        for (int j = 0; j < 4; ++j) {
            const float* bl = bs + (l0 + j) * 32;
            float du = dv0[j] * uu0[j];
            float y = 0.f;
#pragma unroll
            for (int n = 0; n < 16; ++n) {
                float dA = __expf(dv0[j] * A[n]);
                h[n] = dA * h[n] + du * bl[n];
                y += h[n] * bl[16 + n];
            }
            ys[j] = y;
        }
#pragma unroll
        for (int j = 0; j < 4; ++j) dp[(size_t)(l0 + j) * DIM] = ys[j];
#pragma unroll
        for (int j = 0; j < 4; ++j) { dv0[j] = dv1[j]; uu0[j] = uu1[j]; }
    }
}

// ---------------------------------------------------------------------------
// merge 4 directions + D*u + out-LN + silu(z) gate -> yg NHWC (in-place over unh)
__global__ void k_merge(const float* __restrict__ y4, const float* __restrict__ unh,
                        const float* __restrict__ Ds, const float* __restrict__ ong,
                        const float* __restrict__ onb, const float* __restrict__ zt,
                        float* __restrict__ yg)
{
    int lane = threadIdx.x & 63;
    int pix = (blockIdx.x << 2) + (threadIdx.x >> 6);
    int b = pix >> 12, l = pix & (LEN - 1);
    int hh = l >> 6, ww = l & 63;
    int lt = (ww << 6) + hh;
    const float* y0p = y4 + ((size_t)((b * KD + 0) * LEN) + l) * DIM;
    const float* y1p = y4 + ((size_t)((b * KD + 1) * LEN) + lt) * DIM;
    const float* y2p = y4 + ((size_t)((b * KD + 2) * LEN) + (LEN - 1 - l)) * DIM;
    const float* y3p = y4 + ((size_t)((b * KD + 3) * LEN) + (LEN - 1 - lt)) * DIM;
    const float* up  = unh + ((size_t)b * LEN + l) * DIM;
    float v[6]; float s = 0.f, ss = 0.f;
#pragma unroll
    for (int j = 0; j < 6; ++j) {
        int d = lane + (j << 6);
        float y = y0p[d] + y1p[d] + y2p[d] + y3p[d];
        float dsum = Ds[d] + Ds[DIM + d] + Ds[2 * DIM + d] + Ds[3 * DIM + d];
        y += dsum * up[d];
        v[j] = y; s += y; ss += y * y;
    }
#pragma unroll
    for (int off = 1; off < 64; off <<= 1) { s += __shfl_xor(s, off); ss += __shfl_xor(ss, off); }
    float mu = s * (1.f / 384.f);
    float var = ss * (1.f / 384.f) - mu * mu;
    float rstd = rsqrtf(var + 1e-5f);
    const float* zp = zt + (size_t)pix * DIM;
    float* op = yg + (size_t)pix * DIM;
#pragma unroll
    for (int j = 0; j < 6; ++j) {
        int d = lane + (j << 6);
        float zz = zp[d];
        float gate = zz / (1.f + __expf(-zz));
        op[d] = ((v[j] - mu) * rstd * ong[d] + onb[d]) * gate;
    }
}

// ---------------------------------------------------------------------------
extern "C" void kernel_launch(void* const* d_in, const int* in_sizes, int n_in,
                              void* d_out, int out_size, void* d_ws, size_t ws_size,
                              hipStream_t stream)
{
    const float* x    = (const float*)d_in[0];
    const float* c1w  = (const float*)d_in[1];  const float* c1b = (const float*)d_in[2];
    const float* c2w  = (const float*)d_in[3];  const float* c2b = (const float*)d_in[4];
    const float* c3w  = (const float*)d_in[5];  const float* c3b = (const float*)d_in[6];
    const float* c4w  = (const float*)d_in[7];  const float* c4b = (const float*)d_in[8];
    const float* c5w  = (const float*)d_in[9];  const float* c5b = (const float*)d_in[10];
    const float* ln1g = (const float*)d_in[11]; const float* ln1b= (const float*)d_in[12];
    const float* ipw  = (const float*)d_in[13];
    const float* dww  = (const float*)d_in[14]; const float* dwb = (const float*)d_in[15];
    const float* xpw  = (const float*)d_in[16];
    const float* dtw  = (const float*)d_in[17]; const float* dtb = (const float*)d_in[18];
    const float* alog = (const float*)d_in[19]; const float* dsv = (const float*)d_in[20];
    const float* ong  = (const float*)d_in[21]; const float* onb = (const float*)d_in[22];
    const float* opw  = (const float*)d_in[23];
    float* out = (float*)d_out;

    float* ws   = (float*)d_ws;
    float* FN   = ws;                   // (B*L,192) NHWC feature 1,572,864
    float* XN   = FN   + 1572864;       // ln out / conv partials / HF  1,572,864
    float* XP   = XN   + 1572864;       // (B,384,L) planar xp    3,145,728 (PA alias)
    float* ZT   = XP   + 3145728;       // (B*L,384) z NHWC       3,145,728
    float* XCNH = ZT   + 3145728;       // (B*L,384) u NHWC; yg in-place
    float* BCB  = XCNH + 3145728;       // (B,4,L,32)             1,048,576
    float* DLT  = BCB  + 1048576;       // (B,4,L,384) delta->y; YN after merge
    float* WT14 = DLT  + 12582912;      // transformed w c1..c4     129,024
    float* WT5  = WT14 + 129024;        // transformed w c5         110,592
    // total 26,454,016 floats = 105.8 MB
    float* HF = XN;
    float* PA = XP;
    float* PART = XN;                   // conv partials (stage A & c5)
    float* YN = DLT;                    // out_proj output NHWC (B*L,192)

    // weight transforms
    k_wtr<<<dim3(72),  256, 0, stream>>>(c1w, WT14,          64, 32, 9 * 64 * 32);
    k_wtr<<<dim3(108), 256, 0, stream>>>(c2w, WT14 + 18432,  96, 32, 9 * 96 * 32);
    k_wtr<<<dim3(144), 256, 0, stream>>>(c3w, WT14 + 46080, 128, 32, 9 * 128 * 32);
    k_wtr<<<dim3(180), 256, 0, stream>>>(c4w, WT14 + 82944, 160, 32, 9 * 160 * 32);
    k_wtr<<<dim3(432), 256, 0, stream>>>(c5w, WT5,          192, 64, 9 * 192 * 64);

    // stage A: dense conv block (implicit GEMM, NHWC)
    k_tr_in<<<dim3(HN, NB), 256, 0, stream>>>(x, FN);
    k_convg<0><<<dim3(64, 1, NB * 3), 256, 0, stream>>>(FN, DM, 64, WT14, 32, PART);
    k_ep_nhwc<<<dim3(1024), 256, 0, stream>>>(PART, c1b, FN, 64, 0.01f);
    k_convg<0><<<dim3(64, 1, NB * 3), 256, 0, stream>>>(FN, DM, 96, WT14 + 18432, 32, PART);
    k_ep_nhwc<<<dim3(1024), 256, 0, stream>>>(PART, c2b, FN, 96, 0.01f);
    k_convg<0><<<dim3(64, 1, NB * 3), 256, 0, stream>>>(FN, DM, 128, WT14 + 46080, 32, PART);
    k_ep_nhwc<<<dim3(1024), 256, 0, stream>>>(PART, c3b, FN, 128, 0.01f);
    k_convg<0><<<dim3(64, 1, NB * 3), 256, 0, stream>>>(FN, DM, 160, WT14 + 82944, 32, PART);
    k_ep_nhwc<<<dim3(1024), 256, 0, stream>>>(PART, c4b, FN, 160, 0.01f);

    // stage B: VSS block
    k_ln<<<dim3(NB * LEN / 4), 256, 0, stream>>>(FN, ln1g, ln1b, XN);
    k_gemm<<<dim3(LEN / 64, DIM / 64, NB), 256, 0, stream>>>(XN, DM, ipw, nullptr, XP, DIM, 0);
    k_gemm<<<dim3(LEN / 64, DIM / 64, NB), 256, 0, stream>>>(XN, DM, ipw + (size_t)DIM * DM, nullptr, ZT, DIM, 1);
    k_dw<<<dim3(HN, DIM / 64, NB), 256, 0, stream>>>(XP, dww, dwb, XCNH);
    k_xdbl_delta<<<dim3(LEN / 64, KD, NB), 256, 0, stream>>>(XCNH, xpw, dtw, dtb, BCB, DLT);
    k_scan_a<<<dim3(NC, KD, NB), 384, 0, stream>>>(XCNH, BCB, alog, DLT, HF, PA);
    k_scan_b<<<dim3(NB * KD * DIM * NST / 256), 256, 0, stream>>>(HF, PA);
    k_scan_c<<<dim3(NC, KD, NB), 384, 0, stream>>>(XCNH, BCB, alog, HF, DLT);
    k_merge<<<dim3(NB * LEN / 4), 256, 0, stream>>>(DLT, XCNH, dsv, ong, onb, ZT, XCNH);
    k_gemm<<<dim3(LEN / 64, DM / 64, NB), 256, 0, stream>>>(XCNH, DIM, opw, FN, YN, DM, 1);

    // stage C: final conv (implicit GEMM, planar out)
    k_convg<1><<<dim3(64, 2, NB * 3), 256, 0, stream>>>(YN, DM, 192, WT5, 64, PART);
    k_ep_pl<<<dim3(2048), 256, 0, stream>>>(PART, c5b, out);
}

// Round 8
// 536.583 us; speedup vs baseline: 1.4709x; 1.0415x over previous
//
#include <hip/hip_runtime.h>
#include <hip/hip_bf16.h>
#include <math.h>

// ---- problem constants ----
static constexpr int LEN = 4096;   // H*W
static constexpr int HN  = 64;     // H
static constexpr int WN  = 64;     // W
static constexpr int NB  = 2;      // batch
static constexpr int DM  = 192;    // d_model
static constexpr int DIM = 384;    // d_inner
static constexpr int NST = 16;     // n_state
static constexpr int DTR = 12;     // dt_rank
static constexpr int KD  = 4;      // directions
static constexpr int NC  = 32;     // scan chunks
static constexpr int CHL = LEN / NC; // 128 elements per chunk

// direction k seq-position -> pixel row index (uniform across a wave)
__device__ __forceinline__ int maprow(int k, int gl) {
    int g = (k & 2) ? (LEN - 1 - gl) : gl;
    return (k & 1) ? (((g & 63) << 6) | (g >> 6)) : g;
}

// ---------------------------------------------------------------------------
// weight transform: w (co,ci,3,3) -> wt (t, ci, co)
__global__ void k_wtr(const float* __restrict__ w, float* __restrict__ wt,
                      int cin, int cout, int n)
{
    int idx = blockIdx.x * 256 + threadIdx.x;
    if (idx >= n) return;
    int co = idx % cout; int r = idx / cout;
    int ci = r % cin; int t = r / cin;
    wt[idx] = w[((size_t)(co * cin + ci)) * 9 + t];
}

// pad x_proj_w (4,44,384) -> WX (192,384), rows k*48+c (c<44), zero pad
__global__ void k_wxp(const float* __restrict__ xpw, float* __restrict__ WX)
{
    int idx = blockIdx.x * 256 + threadIdx.x;    // 192*384
    if (idx >= 192 * DIM) return;
    int row = idx / DIM, d = idx - row * DIM;
    int k = row / 48, c = row - k * 48;
    WX[idx] = (c < 44) ? xpw[((size_t)(k * 44 + c)) * DIM + d] : 0.f;
}

// ---------------------------------------------------------------------------
// x (B,64,L) planar -> FN NHWC cols [0,64)
__global__ void k_tr_in(const float* __restrict__ x, float* __restrict__ FN)
{
    __shared__ float t[64][65];
    int b = blockIdx.y, r = blockIdx.x;
    int tid = threadIdx.x;
#pragma unroll
    for (int i = 0; i < 16; ++i) {
        int idx = (i << 8) + tid;
        int c = idx >> 6, xc = idx & 63;
        t[c][xc] = x[((size_t)(b * 64 + c)) * LEN + r * WN + xc];
    }
    __syncthreads();
#pragma unroll
    for (int i = 0; i < 16; ++i) {
        int idx = (i << 8) + tid;
        int px = idx >> 6, c = idx & 63;
        FN[((size_t)(b * LEN + r * WN + px)) * DM + c] = t[c][px];
    }
}

// ---------------------------------------------------------------------------
// implicit-GEMM conv3x3, dy-split partials. tile 64px x 32oc, KC=32 ci.
template<int PLANAR>
__global__ void __launch_bounds__(256) k_convg(
    const float* __restrict__ in, int cbuf, int cin,
    const float* __restrict__ wt, int wstride,
    float* __restrict__ part)
{
    __shared__ float As[64][36];
    __shared__ float Bs[32][36];
    int zz = blockIdx.z;
    int b = zz / 3, s = zz % 3;
    int y0 = blockIdx.x;
    int n0 = blockIdx.y << 5;
    int tid = threadIdx.x;
    int tl = tid & 15, tn = (tid >> 4) << 1;
    int y = y0 + s - 1;
    bool yok = (unsigned)y < (unsigned)HN;
    const float* inb = in + ((size_t)b * LEN + (size_t)y * WN) * cbuf;
    float acc[4][2] = {};

    int nchunk = 3 * (cin >> 5);
    for (int cc = 0; cc < nchunk; ++cc) {
        int dx = cc % 3;
        int ci0 = (cc / 3) << 5;
#pragma unroll
        for (int it = 0; it < 2; ++it) {
            int fi = (it << 8) + tid;
            int px = fi >> 3, ci4 = (fi & 7) << 2;
            int xx = px + dx - 1;
            float4 v = make_float4(0.f, 0.f, 0.f, 0.f);
            if (yok && (unsigned)xx < (unsigned)WN)
                v = *(const float4*)(inb + (size_t)xx * cbuf + ci0 + ci4);
            *(float4*)(&As[px][ci4]) = v;
        }
        {
            int fi = tid << 2;
            int ci = fi >> 5, oc = fi & 31;
            int t = s * 3 + dx;
            float4 wv = *(const float4*)(wt + (size_t)(t * cin + ci0 + ci) * wstride + n0 + oc);
            *(float4*)(&Bs[ci][oc]) = wv;
        }
        __syncthreads();
#pragma unroll 8
        for (int k = 0; k < 32; ++k) {
            float b0 = Bs[k][tn], b1 = Bs[k][tn + 1];
#pragma unroll
            for (int i = 0; i < 4; ++i) {
                float a = As[tl + (i << 4)][k];
                acc[i][0] += a * b0;
                acc[i][1] += a * b1;
            }
        }
        __syncthreads();
    }
    if (PLANAR) {
#pragma unroll
        for (int j = 0; j < 2; ++j) {
            float* pp = part + ((size_t)((s * NB + b) * 64 + n0 + tn + j)) * LEN + y0 * WN + tl;
#pragma unroll
            for (int i = 0; i < 4; ++i) pp[i << 4] = acc[i][j];
        }
    } else {
#pragma unroll
        for (int i = 0; i < 4; ++i) {
            float* pp = part + (((size_t)(s * NB + b) * LEN) + y0 * WN + tl + (i << 4)) * 32 + tn;
            pp[0] = acc[i][0]; pp[1] = acc[i][1];
        }
    }
}

// epilogue: sum 3 dy-partials + bias + leakyrelu -> FN NHWC col block
__global__ void k_ep_nhwc(const float* __restrict__ part, const float* __restrict__ bias,
                          float* __restrict__ FN, int co0, float slope)
{
    int idx = blockIdx.x * 256 + threadIdx.x;
    int co = idx & 31, px = idx >> 5;
    const size_t S = (size_t)NB * LEN * 32;
    float v = part[idx] + part[S + idx] + part[2 * S + idx] + bias[co];
    v = v > 0.f ? v : v * slope;
    FN[(size_t)px * DM + co0 + co] = v;
}

// epilogue: sum 3 dy-partials + bias -> planar out (B,64,L)
__global__ void k_ep_pl(const float* __restrict__ part, const float* __restrict__ bias,
                        float* __restrict__ out)
{
    int idx = blockIdx.x * 256 + threadIdx.x;
    int oc = (idx >> 12) & 63;
    const size_t S = (size_t)NB * 64 * LEN;
    float v = part[idx] + part[S + idx] + part[2 * S + idx] + bias[oc];
    out[idx] = v;
}

// ---------------------------------------------------------------------------
// LayerNorm over 192 channels, NHWC in/out
__global__ void k_ln(const float* __restrict__ FN, const float* __restrict__ g,
                     const float* __restrict__ be, float* __restrict__ xn)
{
    int lane = threadIdx.x & 63;
    int pix  = (blockIdx.x << 2) + (threadIdx.x >> 6);
    const float* fp = FN + (size_t)pix * DM;
    float v0 = fp[lane];
    float v1 = fp[lane + 64];
    float v2 = fp[lane + 128];
    float s = v0 + v1 + v2, ss = v0 * v0 + v1 * v1 + v2 * v2;
#pragma unroll
    for (int off = 1; off < 64; off <<= 1) { s += __shfl_xor(s, off); ss += __shfl_xor(ss, off); }
    float mu = s * (1.f / 192.f);
    float var = ss * (1.f / 192.f) - mu * mu;
    float rstd = rsqrtf(var + 1e-5f);
    float* op = xn + (size_t)pix * DM;
    op[lane]       = (v0 - mu) * rstd * g[lane]       + be[lane];
    op[lane + 64]  = (v1 - mu) * rstd * g[lane + 64]  + be[lane + 64];
    op[lane + 128] = (v2 - mu) * rstd * g[lane + 128] + be[lane + 128];
}

// ---------------------------------------------------------------------------
// tiled f32 GEMM: A (B*L, K) NHWC x Wt (N, K) -> planar (B,outC,L) or NHWC.
__global__ void __launch_bounds__(256) k_gemm(
    const float* __restrict__ A, int K,
    const float* __restrict__ Wt,
    const float* __restrict__ res,
    float* __restrict__ Cp, int outC, int nhwc)
{
    __shared__ float As[64][65];
    __shared__ float Bs[64][65];
    int b  = blockIdx.z;
    int l0 = blockIdx.x << 6, n0 = blockIdx.y << 6;
    int tid = threadIdx.x;
    int tl = (tid & 15) << 2, tn = (tid >> 4) << 2;
    float acc[4][4] = {};

    for (int k0 = 0; k0 < K; k0 += 64) {
#pragma unroll
        for (int s = 0; s < 4; ++s) {
            int e = (s << 10) + (tid << 2);
            int row = e >> 6, col = e & 63;
            float4 av = *(const float4*)(A + ((size_t)b * LEN + l0 + row) * K + k0 + col);
            As[row][col] = av.x; As[row][col + 1] = av.y; As[row][col + 2] = av.z; As[row][col + 3] = av.w;
            float4 wv = *(const float4*)(Wt + (size_t)(n0 + row) * K + k0 + col);
            Bs[row][col] = wv.x; Bs[row][col + 1] = wv.y; Bs[row][col + 2] = wv.z; Bs[row][col + 3] = wv.w;
        }
        __syncthreads();
#pragma unroll
        for (int kk = 0; kk < 64; ++kk) {
            float a0 = As[tl][kk], a1 = As[tl + 1][kk], a2 = As[tl + 2][kk], a3 = As[tl + 3][kk];
            float b0 = Bs[tn][kk], b1 = Bs[tn + 1][kk], b2 = Bs[tn + 2][kk], b3 = Bs[tn + 3][kk];
            acc[0][0] += a0 * b0; acc[0][1] += a0 * b1; acc[0][2] += a0 * b2; acc[0][3] += a0 * b3;
            acc[1][0] += a1 * b0; acc[1][1] += a1 * b1; acc[1][2] += a1 * b2; acc[1][3] += a1 * b3;
            acc[2][0] += a2 * b0; acc[2][1] += a2 * b1; acc[2][2] += a2 * b2; acc[2][3] += a2 * b3;
            acc[3][0] += a3 * b0; acc[3][1] += a3 * b1; acc[3][2] += a3 * b2; acc[3][3] += a3 * b3;
        }
        __syncthreads();
    }
    if (!nhwc) {
#pragma unroll
        for (int j = 0; j < 4; ++j) {
            size_t o = ((size_t)(b * outC) + n0 + tn + j) * LEN + l0 + tl;
            float4 v;
            v.x = acc[0][j]; v.y = acc[1][j]; v.z = acc[2][j]; v.w = acc[3][j];
            if (res) {
                float4 r = *(const float4*)(res + o);
                v.x += r.x; v.y += r.y; v.z += r.z; v.w += r.w;
            }
            *(float4*)(Cp + o) = v;
        }
    } else {
#pragma unroll
        for (int i = 0; i < 4; ++i) {
            size_t o = ((size_t)b * LEN + l0 + tl + i) * outC + n0 + tn;
            float4 v;
            v.x = acc[i][0]; v.y = acc[i][1]; v.z = acc[i][2]; v.w = acc[i][3];
            if (res) {
                float4 r = *(const float4*)(res + o);
                v.x += r.x; v.y += r.y; v.z += r.z; v.w += r.w;
            }
            *(float4*)(Cp + o) = v;
        }
    }
}

// ---------------------------------------------------------------------------
// depthwise conv3x3 + SiLU : xp planar (B,384,L) -> unh NHWC (B*L, 384)
__global__ void __launch_bounds__(256) k_dw(
    const float* __restrict__ xp, const float* __restrict__ w,
    const float* __restrict__ bias, float* __restrict__ unh)
{
    __shared__ float t[64][65];
    int b = blockIdx.z, cg = blockIdx.y, r = blockIdx.x;
    int x = threadIdx.x & 63, cs = threadIdx.x >> 6;
#pragma unroll
    for (int i = 0; i < 16; ++i) {
        int c = cg * 64 + cs * 16 + i;
        const float* ip = xp + ((size_t)(b * DIM + c)) * LEN;
        const float* wp = w + c * 9;
        float acc = bias[c];
#pragma unroll
        for (int dy = 0; dy < 3; ++dy) {
            int ry = r + dy - 1;
            if ((unsigned)ry >= (unsigned)HN) continue;
#pragma unroll
            for (int dx = 0; dx < 3; ++dx) {
                int xx = x + dx - 1;
                if ((unsigned)xx >= (unsigned)WN) continue;
                acc += ip[ry * WN + xx] * wp[dy * 3 + dx];
            }
        }
        acc = acc / (1.f + __expf(-acc));
        t[x][cs * 16 + i] = acc;
    }
    __syncthreads();
    float* op = unh + ((size_t)b * LEN + r * 64) * DIM + cg * 64;
#pragma unroll
    for (int i = 0; i < 16; ++i) {
        int idx = (i << 8) + threadIdx.x;
        int px = idx >> 6, cc = idx & 63;
        op[(size_t)px * DIM + cc] = t[px][cc];
    }
}

// ---------------------------------------------------------------------------
// delta = softplus(dtb + CX[:, k*48+0..12] @ dtw[k]^T), pixel-order output
// dlt (B, L, KD, DIM). block = 384 threads (d), 16 pixels per block.
__global__ void __launch_bounds__(384) k_delta(
    const float* __restrict__ CX, const float* __restrict__ dtw,
    const float* __restrict__ dtb, float* __restrict__ dlt)
{
    __shared__ float cs[16][12];
    int b = blockIdx.z, k = blockIdx.y;
    int lp0 = blockIdx.x << 4;
    int tid = threadIdx.x;
    if (tid < 192) {
        int p = tid / 12, r = tid - p * 12;
        cs[p][r] = CX[((size_t)(b * LEN) + lp0 + p) * 192 + k * 48 + r];
    }
    __syncthreads();
    float wt[DTR];
    const float* wp = dtw + ((size_t)(k * DIM) + tid) * DTR;
#pragma unroll
    for (int r = 0; r < DTR; ++r) wt[r] = wp[r];
    float bv = dtb[k * DIM + tid];
    float* dbase = dlt + (((size_t)(b * LEN) + lp0) * KD + k) * DIM + tid;
#pragma unroll
    for (int p = 0; p < 16; ++p) {
        float s = bv;
#pragma unroll
        for (int r = 0; r < DTR; ++r) s += cs[p][r] * wt[r];
        s = (s > 20.f) ? s : __logf(1.f + __expf(s));
        dbase[(size_t)p * KD * DIM] = s;
    }
}

// ---------------------------------------------------------------------------
// chunked scan phase A. thread = d; 16 states in registers; B staged from CX.
// delta/u read at pixel row maprow(k,gl) (coalesced rows).
__global__ void __launch_bounds__(384) k_scan_a(
    const float* __restrict__ unh, const float* __restrict__ CX,
    const float* __restrict__ alog, const float* __restrict__ dlt,
    float* __restrict__ hf, float* __restrict__ pA)
{
    __shared__ float bs[CHL * 16];
    int b = blockIdx.z, k = blockIdx.y, c = blockIdx.x;
    int d = threadIdx.x;
    for (int i = threadIdx.x; i < CHL * 16; i += 384) {
        int l = i >> 4, n = i & 15;
        int row = maprow(k, c * CHL + l);
        bs[i] = CX[((size_t)(b * LEN) + row) * 192 + k * 48 + 12 + n];
    }
    __syncthreads();

    float A[16], h[16], p[16];
    const float* ap = alog + ((size_t)(k * DIM + d)) * NST;
#pragma unroll
    for (int q = 0; q < 4; ++q) {
        float4 av = *(const float4*)(ap + q * 4);
        A[q * 4]     = -__expf(av.x); A[q * 4 + 1] = -__expf(av.y);
        A[q * 4 + 2] = -__expf(av.z); A[q * 4 + 3] = -__expf(av.w);
    }
#pragma unroll
    for (int n = 0; n < 16; ++n) { h[n] = 0.f; p[n] = 1.f; }

    const float* ub = unh + (size_t)b * LEN * DIM + d;
    const float* db = dlt + ((size_t)(b * LEN) * KD + k) * DIM + d;

    for (int l0 = 0; l0 < CHL; l0 += 4) {
        float dv[4], uu[4];
#pragma unroll
        for (int j = 0; j < 4; ++j) {
            int row = maprow(k, c * CHL + l0 + j);
            dv[j] = db[(size_t)row * KD * DIM];
            uu[j] = ub[(size_t)row * DIM];
        }
#pragma unroll
        for (int j = 0; j < 4; ++j) {
            float du = dv[j] * uu[j];
            const float* bl = bs + (l0 + j) * 16;
#pragma unroll
            for (int n = 0; n < 16; ++n) {
                float dA = __expf(dv[j] * A[n]);
                h[n] = dA * h[n] + du * bl[n];
                p[n] *= dA;
            }
        }
    }
    size_t s0 = (((size_t)((b * KD + k) * DIM) + d) * NST) * NC + c;
#pragma unroll
    for (int n = 0; n < 16; ++n) { hf[s0 + (size_t)n * NC] = h[n]; pA[s0 + (size_t)n * NC] = p[n]; }
}

// phase B: serial carry combine over chunks; hf[c] overwritten with carry-IN.
__global__ void k_scan_b(float* __restrict__ hf, const float* __restrict__ pA)
{
    int s = blockIdx.x * 256 + threadIdx.x;
    float* hp = hf + (size_t)s * NC;
    const float* pp = pA + (size_t)s * NC;
    float car = 0.f;
#pragma unroll
    for (int c = 0; c < NC; ++c) {
        float hfc = hp[c], pc = pp[c];
        hp[c] = car;
        car = pc * car + hfc;
    }
}

// phase C: re-run chunk from carry-in; y written at pixel-order location
// (same row it read delta from) so merge reads all 4 k contiguously.
__global__ void __launch_bounds__(384) k_scan_c(
    const float* __restrict__ unh, const float* __restrict__ CX,
    const float* __restrict__ alog, const float* __restrict__ hf,
    float* __restrict__ dlt)
{
    __shared__ float bs[CHL * 32];
    int b = blockIdx.z, k = blockIdx.y, c = blockIdx.x;
    int d = threadIdx.x;
    for (int i = threadIdx.x; i < CHL * 32; i += 384) {
        int l = i >> 5, n = i & 31;
        int row = maprow(k, c * CHL + l);
        bs[i] = CX[((size_t)(b * LEN) + row) * 192 + k * 48 + 12 + n];
    }
    __syncthreads();

    float A[16], h[16];
    const float* ap = alog + ((size_t)(k * DIM + d)) * NST;
#pragma unroll
    for (int q = 0; q < 4; ++q) {
        float4 av = *(const float4*)(ap + q * 4);
        A[q * 4]     = -__expf(av.x); A[q * 4 + 1] = -__expf(av.y);
        A[q * 4 + 2] = -__expf(av.z); A[q * 4 + 3] = -__expf(av.w);
    }
    size_t s0 = (((size_t)((b * KD + k) * DIM) + d) * NST) * NC + c;
#pragma unroll
    for (int n = 0; n < 16; ++n) h[n] = hf[s0 + (size_t)n * NC];

    const float* ub = unh + (size_t)b * LEN * DIM + d;
    float* db = dlt + ((size_t)(b * LEN) * KD + k) * DIM + d;

    int rows0[4], rows1[4];
    float dv0[4], uu0[4], dv1[4], uu1[4];
#pragma unroll
    for (int j = 0; j < 4; ++j) {
        rows0[j] = maprow(k, c * CHL + j);
        dv0[j] = db[(size_t)rows0[j] * KD * DIM];
        uu0[j] = ub[(size_t)rows0[j] * DIM];
    }
    for (int l0 = 0; l0 < CHL; l0 += 4) {
        if (l0 + 4 < CHL) {
#pragma unroll
            for (int j = 0; j < 4; ++j) {
                rows1[j] = maprow(k, c * CHL + l0 + 4 + j);
                dv1[j] = db[(size_t)rows1[j] * KD * DIM];
                uu1[j] = ub[(size_t)rows1[j] * DIM];
            }
        }
        float ys[4];
#pragma unroll
        for (int j = 0; j < 4; ++j) {
            const float* bl = bs + (l0 + j) * 32;
            float du = dv0[j] * uu0[j];
            float y = 0.f;
#pragma unroll
            for (int n = 0; n < 16; ++n) {
                float dA = __expf(dv0[j] * A[n]);
                h[n] = dA * h[n] + du * bl[n];
                y += h[n] * bl[16 + n];
            }
            ys[j] = y;
        }
#pragma unroll
        for (int j = 0; j < 4; ++j) db[(size_t)rows0[j] * KD * DIM] = ys[j];
#pragma unroll
        for (int j = 0; j < 4; ++j) { rows0[j] = rows1[j]; dv0[j] = dv1[j]; uu0[j] = uu1[j]; }
    }
}

// ---------------------------------------------------------------------------
// merge 4 directions + D*u + out-LN + silu(z) gate -> yg NHWC (in-place over unh)
// y4 pixel-order (B, L, KD, DIM): all 4 directions contiguous per pixel.
__global__ void k_merge(const float* __restrict__ y4, const float* __restrict__ unh,
                        const float* __restrict__ Ds, const float* __restrict__ ong,
                        const float* __restrict__ onb, const float* __restrict__ zt,
                        float* __restrict__ yg)
{
    int lane = threadIdx.x & 63;
    int pix = (blockIdx.x << 2) + (threadIdx.x >> 6);
    const float* yp = y4 + (size_t)pix * KD * DIM;
    const float* up = unh + (size_t)pix * DIM;
    float v[6]; float s = 0.f, ss = 0.f;
#pragma unroll
    for (int j = 0; j < 6; ++j) {
        int d = lane + (j << 6);
        float y = yp[d] + yp[DIM + d] + yp[2 * DIM + d] + yp[3 * DIM + d];
        float dsum = Ds[d] + Ds[DIM + d] + Ds[2 * DIM + d] + Ds[3 * DIM + d];
        y += dsum * up[d];
        v[j] = y; s += y; ss += y * y;
    }
#pragma unroll
    for (int off = 1; off < 64; off <<= 1) { s += __shfl_xor(s, off); ss += __shfl_xor(ss, off); }
    float mu = s * (1.f / 384.f);
    float var = ss * (1.f / 384.f) - mu * mu;
    float rstd = rsqrtf(var + 1e-5f);
    const float* zp = zt + (size_t)pix * DIM;
    float* op = yg + (size_t)pix * DIM;
#pragma unroll
    for (int j = 0; j < 6; ++j) {
        int d = lane + (j << 6);
        float zz = zp[d];
        float gate = zz / (1.f + __expf(-zz));
        op[d] = ((v[j] - mu) * rstd * ong[d] + onb[d]) * gate;
    }
}

// ---------------------------------------------------------------------------
extern "C" void kernel_launch(void* const* d_in, const int* in_sizes, int n_in,
                              void* d_out, int out_size, void* d_ws, size_t ws_size,
                              hipStream_t stream)
{
    const float* x    = (const float*)d_in[0];
    const float* c1w  = (const float*)d_in[1];  const float* c1b = (const float*)d_in[2];
    const float* c2w  = (const float*)d_in[3];  const float* c2b = (const float*)d_in[4];
    const float* c3w  = (const float*)d_in[5];  const float* c3b = (const float*)d_in[6];
    const float* c4w  = (const float*)d_in[7];  const float* c4b = (const float*)d_in[8];
    const float* c5w  = (const float*)d_in[9];  const float* c5b = (const float*)d_in[10];
    const float* ln1g = (const float*)d_in[11]; const float* ln1b= (const float*)d_in[12];
    const float* ipw  = (const float*)d_in[13];
    const float* dww  = (const float*)d_in[14]; const float* dwb = (const float*)d_in[15];
    const float* xpw  = (const float*)d_in[16];
    const float* dtw  = (const float*)d_in[17]; const float* dtb = (const float*)d_in[18];
    const float* alog = (const float*)d_in[19]; const float* dsv = (const float*)d_in[20];
    const float* ong  = (const float*)d_in[21]; const float* onb = (const float*)d_in[22];
    const float* opw  = (const float*)d_in[23];
    float* out = (float*)d_out;

    float* ws   = (float*)d_ws;
    float* FN   = ws;                   // (B*L,192) NHWC feature 1,572,864
    float* XN   = FN   + 1572864;       // ln out / conv partials / HF
    float* XP   = XN   + 1572864;       // (B,384,L) planar xp; PA+CX after dw
    float* ZT   = XP   + 3145728;       // (B*L,384) z NHWC
    float* XCNH = ZT   + 3145728;       // (B*L,384) u NHWC; yg in-place
    float* DLT  = XCNH + 3145728;       // (B,L,4,384) delta->y pixel-order; YN after
    float* WT14 = DLT  + 12582912;      // transformed w c1..c4     129,024
    float* WT5  = WT14 + 129024;        // transformed w c5         110,592
    float* WX   = WT5  + 110592;        // padded x_proj_w (192,384) 73,728
    // total ~25.5M floats = 102 MB
    float* HF = XN;
    float* PA = XP;                     // [0 : 1.57M) of XP
    float* CX = XP + 1572864;           // [1.57M : 3.14M) of XP
    float* PART = XN;                   // conv partials (stage A & c5)
    float* YN = DLT;                    // out_proj output NHWC (B*L,192)

    // weight transforms
    k_wtr<<<dim3(72),  256, 0, stream>>>(c1w, WT14,          64, 32, 9 * 64 * 32);
    k_wtr<<<dim3(108), 256, 0, stream>>>(c2w, WT14 + 18432,  96, 32, 9 * 96 * 32);
    k_wtr<<<dim3(144), 256, 0, stream>>>(c3w, WT14 + 46080, 128, 32, 9 * 128 * 32);
    k_wtr<<<dim3(180), 256, 0, stream>>>(c4w, WT14 + 82944, 160, 32, 9 * 160 * 32);
    k_wtr<<<dim3(432), 256, 0, stream>>>(c5w, WT5,          192, 64, 9 * 192 * 64);
    k_wxp<<<dim3(288), 256, 0, stream>>>(xpw, WX);

    // stage A: dense conv block (implicit GEMM, NHWC)
    k_tr_in<<<dim3(HN, NB), 256, 0, stream>>>(x, FN);
    k_convg<0><<<dim3(64, 1, NB * 3), 256, 0, stream>>>(FN, DM, 64, WT14, 32, PART);
    k_ep_nhwc<<<dim3(1024), 256, 0, stream>>>(PART, c1b, FN, 64, 0.01f);
    k_convg<0><<<dim3(64, 1, NB * 3), 256, 0, stream>>>(FN, DM, 96, WT14 + 18432, 32, PART);
    k_ep_nhwc<<<dim3(1024), 256, 0, stream>>>(PART, c2b, FN, 96, 0.01f);
    k_convg<0><<<dim3(64, 1, NB * 3), 256, 0, stream>>>(FN, DM, 128, WT14 + 46080, 32, PART);
    k_ep_nhwc<<<dim3(1024), 256, 0, stream>>>(PART, c3b, FN, 128, 0.01f);
    k_convg<0><<<dim3(64, 1, NB * 3), 256, 0, stream>>>(FN, DM, 160, WT14 + 82944, 32, PART);
    k_ep_nhwc<<<dim3(1024), 256, 0, stream>>>(PART, c4b, FN, 160, 0.01f);

    // stage B: VSS block
    k_ln<<<dim3(NB * LEN / 4), 256, 0, stream>>>(FN, ln1g, ln1b, XN);
    k_gemm<<<dim3(LEN / 64, DIM / 64, NB), 256, 0, stream>>>(XN, DM, ipw, nullptr, XP, DIM, 0);
    k_gemm<<<dim3(LEN / 64, DIM / 64, NB), 256, 0, stream>>>(XN, DM, ipw + (size_t)DIM * DM, nullptr, ZT, DIM, 1);
    k_dw<<<dim3(HN, DIM / 64, NB), 256, 0, stream>>>(XP, dww, dwb, XCNH);
    k_gemm<<<dim3(LEN / 64, 3, NB), 256, 0, stream>>>(XCNH, DIM, WX, nullptr, CX, 192, 1);
    k_delta<<<dim3(LEN / 16, KD, NB), 384, 0, stream>>>(CX, dtw, dtb, DLT);
    k_scan_a<<<dim3(NC, KD, NB), 384, 0, stream>>>(XCNH, CX, alog, DLT, HF, PA);
    k_scan_b<<<dim3(NB * KD * DIM * NST / 256), 256, 0, stream>>>(HF, PA);
    k_scan_c<<<dim3(NC, KD, NB), 384, 0, stream>>>(XCNH, CX, alog, HF, DLT);
    k_merge<<<dim3(NB * LEN / 4), 256, 0, stream>>>(DLT, XCNH, dsv, ong, onb, ZT, XCNH);
    k_gemm<<<dim3(LEN / 64, DM / 64, NB), 256, 0, stream>>>(XCNH, DIM, opw, FN, YN, DM, 1);

    // stage C: final conv (implicit GEMM, planar out)
    k_convg<1><<<dim3(64, 2, NB * 3), 256, 0, stream>>>(YN, DM, 192, WT5, 64, PART);
    k_ep_pl<<<dim3(2048), 256, 0, stream>>>(PART, c5b, out);
}

// Round 9
// 483.029 us; speedup vs baseline: 1.6340x; 1.1109x over previous
//
#include <hip/hip_runtime.h>
#include <hip/hip_bf16.h>
#include <math.h>

// ---- problem constants ----
static constexpr int LEN = 4096;   // H*W
static constexpr int HN  = 64;     // H
static constexpr int WN  = 64;     // W
static constexpr int NB  = 2;      // batch
static constexpr int DM  = 192;    // d_model
static constexpr int DIM = 384;    // d_inner
static constexpr int NST = 16;     // n_state
static constexpr int DTR = 12;     // dt_rank
static constexpr int KD  = 4;      // directions
static constexpr int NC  = 64;     // scan chunks
static constexpr int CHL = LEN / NC; // 64 elements per chunk

// direction k seq-position -> pixel row index (uniform across a wave)
__device__ __forceinline__ int maprow(int k, int gl) {
    int g = (k & 2) ? (LEN - 1 - gl) : gl;
    return (k & 1) ? (((g & 63) << 6) | (g >> 6)) : g;
}

// ---------------------------------------------------------------------------
// weight transform: w (co,ci,3,3) -> wt (t, ci, co)
__global__ void k_wtr(const float* __restrict__ w, float* __restrict__ wt,
                      int cin, int cout, int n)
{
    int idx = blockIdx.x * 256 + threadIdx.x;
    if (idx >= n) return;
    int co = idx % cout; int r = idx / cout;
    int ci = r % cin; int t = r / cin;
    wt[idx] = w[((size_t)(co * cin + ci)) * 9 + t];
}

// pad x_proj_w (4,44,384) -> WX (192,384), rows k*48+c (c<44), zero pad
__global__ void k_wxp(const float* __restrict__ xpw, float* __restrict__ WX)
{
    int idx = blockIdx.x * 256 + threadIdx.x;    // 192*384
    if (idx >= 192 * DIM) return;
    int row = idx / DIM, d = idx - row * DIM;
    int k = row / 48, c = row - k * 48;
    WX[idx] = (c < 44) ? xpw[((size_t)(k * 44 + c)) * DIM + d] : 0.f;
}

// ---------------------------------------------------------------------------
// x (B,64,L) planar -> FN NHWC cols [0,64)
__global__ void k_tr_in(const float* __restrict__ x, float* __restrict__ FN)
{
    __shared__ float t[64][65];
    int b = blockIdx.y, r = blockIdx.x;
    int tid = threadIdx.x;
#pragma unroll
    for (int i = 0; i < 16; ++i) {
        int idx = (i << 8) + tid;
        int c = idx >> 6, xc = idx & 63;
        t[c][xc] = x[((size_t)(b * 64 + c)) * LEN + r * WN + xc];
    }
    __syncthreads();
#pragma unroll
    for (int i = 0; i < 16; ++i) {
        int idx = (i << 8) + tid;
        int px = idx >> 6, c = idx & 63;
        FN[((size_t)(b * LEN + r * WN + px)) * DM + c] = t[c][px];
    }
}

// ---------------------------------------------------------------------------
// implicit-GEMM conv3x3, dy-split partials. tile 64px x 32oc, KC=32 ci.
template<int PLANAR>
__global__ void __launch_bounds__(256) k_convg(
    const float* __restrict__ in, int cbuf, int cin,
    const float* __restrict__ wt, int wstride,
    float* __restrict__ part)
{
    __shared__ float As[64][36];
    __shared__ float Bs[32][36];
    int zz = blockIdx.z;
    int b = zz / 3, s = zz % 3;
    int y0 = blockIdx.x;
    int n0 = blockIdx.y << 5;
    int tid = threadIdx.x;
    int tl = tid & 15, tn = (tid >> 4) << 1;
    int y = y0 + s - 1;
    bool yok = (unsigned)y < (unsigned)HN;
    const float* inb = in + ((size_t)b * LEN + (size_t)y * WN) * cbuf;
    float acc[4][2] = {};

    int nchunk = 3 * (cin >> 5);
    for (int cc = 0; cc < nchunk; ++cc) {
        int dx = cc % 3;
        int ci0 = (cc / 3) << 5;
#pragma unroll
        for (int it = 0; it < 2; ++it) {
            int fi = (it << 8) + tid;
            int px = fi >> 3, ci4 = (fi & 7) << 2;
            int xx = px + dx - 1;
            float4 v = make_float4(0.f, 0.f, 0.f, 0.f);
            if (yok && (unsigned)xx < (unsigned)WN)
                v = *(const float4*)(inb + (size_t)xx * cbuf + ci0 + ci4);
            *(float4*)(&As[px][ci4]) = v;
        }
        {
            int fi = tid << 2;
            int ci = fi >> 5, oc = fi & 31;
            int t = s * 3 + dx;
            float4 wv = *(const float4*)(wt + (size_t)(t * cin + ci0 + ci) * wstride + n0 + oc);
            *(float4*)(&Bs[ci][oc]) = wv;
        }
        __syncthreads();
#pragma unroll 8
        for (int k = 0; k < 32; ++k) {
            float b0 = Bs[k][tn], b1 = Bs[k][tn + 1];
#pragma unroll
            for (int i = 0; i < 4; ++i) {
                float a = As[tl + (i << 4)][k];
                acc[i][0] += a * b0;
                acc[i][1] += a * b1;
            }
        }
        __syncthreads();
    }
    if (PLANAR) {
#pragma unroll
        for (int j = 0; j < 2; ++j) {
            float* pp = part + ((size_t)((s * NB + b) * 64 + n0 + tn + j)) * LEN + y0 * WN + tl;
#pragma unroll
            for (int i = 0; i < 4; ++i) pp[i << 4] = acc[i][j];
        }
    } else {
#pragma unroll
        for (int i = 0; i < 4; ++i) {
            float* pp = part + (((size_t)(s * NB + b) * LEN) + y0 * WN + tl + (i << 4)) * 32 + tn;
            pp[0] = acc[i][0]; pp[1] = acc[i][1];
        }
    }
}

// epilogue: sum 3 dy-partials + bias + leakyrelu -> FN NHWC col block
__global__ void k_ep_nhwc(const float* __restrict__ part, const float* __restrict__ bias,
                          float* __restrict__ FN, int co0, float slope)
{
    int idx = blockIdx.x * 256 + threadIdx.x;
    int co = idx & 31, px = idx >> 5;
    const size_t S = (size_t)NB * LEN * 32;
    float v = part[idx] + part[S + idx] + part[2 * S + idx] + bias[co];
    v = v > 0.f ? v : v * slope;
    FN[(size_t)px * DM + co0 + co] = v;
}

// epilogue: sum 3 dy-partials + bias -> planar out (B,64,L)
__global__ void k_ep_pl(const float* __restrict__ part, const float* __restrict__ bias,
                        float* __restrict__ out)
{
    int idx = blockIdx.x * 256 + threadIdx.x;
    int oc = (idx >> 12) & 63;
    const size_t S = (size_t)NB * 64 * LEN;
    float v = part[idx] + part[S + idx] + part[2 * S + idx] + bias[oc];
    out[idx] = v;
}

// ---------------------------------------------------------------------------
// LayerNorm over 192 channels, NHWC in/out
__global__ void k_ln(const float* __restrict__ FN, const float* __restrict__ g,
                     const float* __restrict__ be, float* __restrict__ xn)
{
    int lane = threadIdx.x & 63;
    int pix  = (blockIdx.x << 2) + (threadIdx.x >> 6);
    const float* fp = FN + (size_t)pix * DM;
    float v0 = fp[lane];
    float v1 = fp[lane + 64];
    float v2 = fp[lane + 128];
    float s = v0 + v1 + v2, ss = v0 * v0 + v1 * v1 + v2 * v2;
#pragma unroll
    for (int off = 1; off < 64; off <<= 1) { s += __shfl_xor(s, off); ss += __shfl_xor(ss, off); }
    float mu = s * (1.f / 192.f);
    float var = ss * (1.f / 192.f) - mu * mu;
    float rstd = rsqrtf(var + 1e-5f);
    float* op = xn + (size_t)pix * DM;
    op[lane]       = (v0 - mu) * rstd * g[lane]       + be[lane];
    op[lane + 64]  = (v1 - mu) * rstd * g[lane + 64]  + be[lane + 64];
    op[lane + 128] = (v2 - mu) * rstd * g[lane + 128] + be[lane + 128];
}

// ---------------------------------------------------------------------------
// tiled f32 GEMM: A (B*L, K) NHWC x Wt (N, K) -> planar (B,outC,L) or NHWC.
__global__ void __launch_bounds__(256) k_gemm(
    const float* __restrict__ A, int K,
    const float* __restrict__ Wt,
    const float* __restrict__ res,
    float* __restrict__ Cp, int outC, int nhwc)
{
    __shared__ float As[64][65];
    __shared__ float Bs[64][65];
    int b  = blockIdx.z;
    int l0 = blockIdx.x << 6, n0 = blockIdx.y << 6;
    int tid = threadIdx.x;
    int tl = (tid & 15) << 2, tn = (tid >> 4) << 2;
    float acc[4][4] = {};

    for (int k0 = 0; k0 < K; k0 += 64) {
#pragma unroll
        for (int s = 0; s < 4; ++s) {
            int e = (s << 10) + (tid << 2);
            int row = e >> 6, col = e & 63;
            float4 av = *(const float4*)(A + ((size_t)b * LEN + l0 + row) * K + k0 + col);
            As[row][col] = av.x; As[row][col + 1] = av.y; As[row][col + 2] = av.z; As[row][col + 3] = av.w;
            float4 wv = *(const float4*)(Wt + (size_t)(n0 + row) * K + k0 + col);
            Bs[row][col] = wv.x; Bs[row][col + 1] = wv.y; Bs[row][col + 2] = wv.z; Bs[row][col + 3] = wv.w;
        }
        __syncthreads();
#pragma unroll
        for (int kk = 0; kk < 64; ++kk) {
            float a0 = As[tl][kk], a1 = As[tl + 1][kk], a2 = As[tl + 2][kk], a3 = As[tl + 3][kk];
            float b0 = Bs[tn][kk], b1 = Bs[tn + 1][kk], b2 = Bs[tn + 2][kk], b3 = Bs[tn + 3][kk];
            acc[0][0] += a0 * b0; acc[0][1] += a0 * b1; acc[0][2] += a0 * b2; acc[0][3] += a0 * b3;
            acc[1][0] += a1 * b0; acc[1][1] += a1 * b1; acc[1][2] += a1 * b2; acc[1][3] += a1 * b3;
            acc[2][0] += a2 * b0; acc[2][1] += a2 * b1; acc[2][2] += a2 * b2; acc[2][3] += a2 * b3;
            acc[3][0] += a3 * b0; acc[3][1] += a3 * b1; acc[3][2] += a3 * b2; acc[3][3] += a3 * b3;
        }
        __syncthreads();
    }
    if (!nhwc) {
#pragma unroll
        for (int j = 0; j < 4; ++j) {
            size_t o = ((size_t)(b * outC) + n0 + tn + j) * LEN + l0 + tl;
            float4 v;
            v.x = acc[0][j]; v.y = acc[1][j]; v.z = acc[2][j]; v.w = acc[3][j];
            if (res) {
                float4 r = *(const float4*)(res + o);
                v.x += r.x; v.y += r.y; v.z += r.z; v.w += r.w;
            }
            *(float4*)(Cp + o) = v;
        }
    } else {
#pragma unroll
        for (int i = 0; i < 4; ++i) {
            size_t o = ((size_t)b * LEN + l0 + tl + i) * outC + n0 + tn;
            float4 v;
            v.x = acc[i][0]; v.y = acc[i][1]; v.z = acc[i][2]; v.w = acc[i][3];
            if (res) {
                float4 r = *(const float4*)(res + o);
                v.x += r.x; v.y += r.y; v.z += r.z; v.w += r.w;
            }
            *(float4*)(Cp + o) = v;
        }
    }
}

// ---------------------------------------------------------------------------
// depthwise conv3x3 + SiLU : xp planar (B,384,L) -> unh NHWC (B*L, 384)
__global__ void __launch_bounds__(256) k_dw(
    const float* __restrict__ xp, const float* __restrict__ w,
    const float* __restrict__ bias, float* __restrict__ unh)
{
    __shared__ float t[64][65];
    int b = blockIdx.z, cg = blockIdx.y, r = blockIdx.x;
    int x = threadIdx.x & 63, cs = threadIdx.x >> 6;
#pragma unroll
    for (int i = 0; i < 16; ++i) {
        int c = cg * 64 + cs * 16 + i;
        const float* ip = xp + ((size_t)(b * DIM + c)) * LEN;
        const float* wp = w + c * 9;
        float acc = bias[c];
#pragma unroll
        for (int dy = 0; dy < 3; ++dy) {
            int ry = r + dy - 1;
            if ((unsigned)ry >= (unsigned)HN) continue;
#pragma unroll
            for (int dx = 0; dx < 3; ++dx) {
                int xx = x + dx - 1;
                if ((unsigned)xx >= (unsigned)WN) continue;
                acc += ip[ry * WN + xx] * wp[dy * 3 + dx];
            }
        }
        acc = acc / (1.f + __expf(-acc));
        t[x][cs * 16 + i] = acc;
    }
    __syncthreads();
    float* op = unh + ((size_t)b * LEN + r * 64) * DIM + cg * 64;
#pragma unroll
    for (int i = 0; i < 16; ++i) {
        int idx = (i << 8) + threadIdx.x;
        int px = idx >> 6, cc = idx & 63;
        op[(size_t)px * DIM + cc] = t[px][cc];
    }
}

// ---------------------------------------------------------------------------
// delta = softplus(dtb + CX[:, k*48+0..12] @ dtw[k]^T), pixel-order output
__global__ void __launch_bounds__(384) k_delta(
    const float* __restrict__ CX, const float* __restrict__ dtw,
    const float* __restrict__ dtb, float* __restrict__ dlt)
{
    __shared__ float cs[16][12];
    int b = blockIdx.z, k = blockIdx.y;
    int lp0 = blockIdx.x << 4;
    int tid = threadIdx.x;
    if (tid < 192) {
        int p = tid / 12, r = tid - p * 12;
        cs[p][r] = CX[((size_t)(b * LEN) + lp0 + p) * 192 + k * 48 + r];
    }
    __syncthreads();
    float wt[DTR];
    const float* wp = dtw + ((size_t)(k * DIM) + tid) * DTR;
#pragma unroll
    for (int r = 0; r < DTR; ++r) wt[r] = wp[r];
    float bv = dtb[k * DIM + tid];
    float* dbase = dlt + (((size_t)(b * LEN) + lp0) * KD + k) * DIM + tid;
#pragma unroll
    for (int p = 0; p < 16; ++p) {
        float s = bv;
#pragma unroll
        for (int r = 0; r < DTR; ++r) s += cs[p][r] * wt[r];
        s = (s > 20.f) ? s : __logf(1.f + __expf(s));
        dbase[(size_t)p * KD * DIM] = s;
    }
}

// ---------------------------------------------------------------------------
// chunked scan phase A. thread = d; 16 states in registers; B staged from CX.
// carry layout: hf/pA[((bk*NC + c)*NST + n)*DIM + d]  (coalesced stores)
__global__ void __launch_bounds__(384) k_scan_a(
    const float* __restrict__ unh, const float* __restrict__ CX,
    const float* __restrict__ alog, const float* __restrict__ dlt,
    float* __restrict__ hf, float* __restrict__ pA)
{
    __shared__ float bs[CHL * 16];
    int b = blockIdx.z, k = blockIdx.y, c = blockIdx.x;
    int d = threadIdx.x;
    for (int i = threadIdx.x; i < CHL * 16; i += 384) {
        int l = i >> 4, n = i & 15;
        int row = maprow(k, c * CHL + l);
        bs[i] = CX[((size_t)(b * LEN) + row) * 192 + k * 48 + 12 + n];
    }
    __syncthreads();

    float A[16], h[16], p[16];
    const float* ap = alog + ((size_t)(k * DIM + d)) * NST;
#pragma unroll
    for (int q = 0; q < 4; ++q) {
        float4 av = *(const float4*)(ap + q * 4);
        A[q * 4]     = -__expf(av.x); A[q * 4 + 1] = -__expf(av.y);
        A[q * 4 + 2] = -__expf(av.z); A[q * 4 + 3] = -__expf(av.w);
    }
#pragma unroll
    for (int n = 0; n < 16; ++n) { h[n] = 0.f; p[n] = 1.f; }

    const float* ub = unh + (size_t)b * LEN * DIM + d;
    const float* db = dlt + ((size_t)(b * LEN) * KD + k) * DIM + d;

    float dv0[4], uu0[4], dv1[4], uu1[4];
#pragma unroll
    for (int j = 0; j < 4; ++j) {
        int row = maprow(k, c * CHL + j);
        dv0[j] = db[(size_t)row * KD * DIM];
        uu0[j] = ub[(size_t)row * DIM];
    }
    for (int l0 = 0; l0 < CHL; l0 += 4) {
        if (l0 + 4 < CHL) {
#pragma unroll
            for (int j = 0; j < 4; ++j) {
                int row = maprow(k, c * CHL + l0 + 4 + j);
                dv1[j] = db[(size_t)row * KD * DIM];
                uu1[j] = ub[(size_t)row * DIM];
            }
        }
#pragma unroll
        for (int j = 0; j < 4; ++j) {
            float du = dv0[j] * uu0[j];
            const float* bl = bs + (l0 + j) * 16;
#pragma unroll
            for (int n = 0; n < 16; ++n) {
                float dA = __expf(dv0[j] * A[n]);
                h[n] = dA * h[n] + du * bl[n];
                p[n] *= dA;
            }
        }
#pragma unroll
        for (int j = 0; j < 4; ++j) { dv0[j] = dv1[j]; uu0[j] = uu1[j]; }
    }
    size_t base = (((size_t)((b * KD + k) * NC + c)) * NST) * DIM + d;
#pragma unroll
    for (int n = 0; n < 16; ++n) {
        hf[base + (size_t)n * DIM] = h[n];
        pA[base + (size_t)n * DIM] = p[n];
    }
}

// phase B: serial carry combine over chunks; hf[c] overwritten with carry-IN.
// state s = bk*(NST*DIM) + r; address = bk*NC*NST*DIM + c*NST*DIM + r (coalesced).
__global__ void k_scan_b(float* __restrict__ hf, const float* __restrict__ pA)
{
    int s = blockIdx.x * 256 + threadIdx.x;          // NB*KD*NST*DIM = 49152
    int bk = s / (NST * DIM);
    int r  = s - bk * (NST * DIM);
    size_t base = (size_t)bk * NC * NST * DIM + r;
    const size_t cs = (size_t)NST * DIM;
    float car = 0.f;
#pragma unroll 8
    for (int c = 0; c < NC; ++c) {
        float hfc = hf[base + c * cs], pc = pA[base + c * cs];
        hf[base + c * cs] = car;
        car = pc * car + hfc;
    }
}

// phase C: re-run chunk from carry-in; y written at pixel-order location.
__global__ void __launch_bounds__(384) k_scan_c(
    const float* __restrict__ unh, const float* __restrict__ CX,
    const float* __restrict__ alog, const float* __restrict__ hf,
    float* __restrict__ dlt)
{
    __shared__ float bs[CHL * 32];
    int b = blockIdx.z, k = blockIdx.y, c = blockIdx.x;
    int d = threadIdx.x;
    for (int i = threadIdx.x; i < CHL * 32; i += 384) {
        int l = i >> 5, n = i & 31;
        int row = maprow(k, c * CHL + l);
        bs[i] = CX[((size_t)(b * LEN) + row) * 192 + k * 48 + 12 + n];
    }
    __syncthreads();

    float A[16], h[16];
    const float* ap = alog + ((size_t)(k * DIM + d)) * NST;
#pragma unroll
    for (int q = 0; q < 4; ++q) {
        float4 av = *(const float4*)(ap + q * 4);
        A[q * 4]     = -__expf(av.x); A[q * 4 + 1] = -__expf(av.y);
        A[q * 4 + 2] = -__expf(av.z); A[q * 4 + 3] = -__expf(av.w);
    }
    size_t base = (((size_t)((b * KD + k) * NC + c)) * NST) * DIM + d;
#pragma unroll
    for (int n = 0; n < 16; ++n) h[n] = hf[base + (size_t)n * DIM];

    const float* ub = unh + (size_t)b * LEN * DIM + d;
    float* db = dlt + ((size_t)(b * LEN) * KD + k) * DIM + d;

    int rows0[4], rows1[4];
    float dv0[4], uu0[4], dv1[4], uu1[4];
#pragma unroll
    for (int j = 0; j < 4; ++j) {
        rows0[j] = maprow(k, c * CHL + j);
        dv0[j] = db[(size_t)rows0[j] * KD * DIM];
        uu0[j] = ub[(size_t)rows0[j] * DIM];
    }
    for (int l0 = 0; l0 < CHL; l0 += 4) {
        if (l0 + 4 < CHL) {
#pragma unroll
            for (int j = 0; j < 4; ++j) {
                rows1[j] = maprow(k, c * CHL + l0 + 4 + j);
                dv1[j] = db[(size_t)rows1[j] * KD * DIM];
                uu1[j] = ub[(size_t)rows1[j] * DIM];
            }
        }
        float ys[4];
#pragma unroll
        for (int j = 0; j < 4; ++j) {
            const float* bl = bs + (l0 + j) * 32;
            float du = dv0[j] * uu0[j];
            float y = 0.f;
#pragma unroll
            for (int n = 0; n < 16; ++n) {
                float dA = __expf(dv0[j] * A[n]);
                h[n] = dA * h[n] + du * bl[n];
                y += h[n] * bl[16 + n];
            }
            ys[j] = y;
        }
#pragma unroll
        for (int j = 0; j < 4; ++j) db[(size_t)rows0[j] * KD * DIM] = ys[j];
#pragma unroll
        for (int j = 0; j < 4; ++j) { rows0[j] = rows1[j]; dv0[j] = dv1[j]; uu0[j] = uu1[j]; }
    }
}

// ---------------------------------------------------------------------------
// merge 4 directions + D*u + out-LN + silu(z) gate -> yg NHWC (in-place over unh)
__global__ void k_merge(const float* __restrict__ y4, const float* __restrict__ unh,
                        const float* __restrict__ Ds, const float* __restrict__ ong,
                        const float* __restrict__ onb, const float* __restrict__ zt,
                        float* __restrict__ yg)
{
    int lane = threadIdx.x & 63;
    int pix = (blockIdx.x << 2) + (threadIdx.x >> 6);
    const float* yp = y4 + (size_t)pix * KD * DIM;
    const float* up = unh + (size_t)pix * DIM;
    float v[6]; float s = 0.f, ss = 0.f;
#pragma unroll
    for (int j = 0; j < 6; ++j) {
        int d = lane + (j << 6);
        float y = yp[d] + yp[DIM + d] + yp[2 * DIM + d] + yp[3 * DIM + d];
        float dsum = Ds[d] + Ds[DIM + d] + Ds[2 * DIM + d] + Ds[3 * DIM + d];
        y += dsum * up[d];
        v[j] = y; s += y; ss += y * y;
    }
#pragma unroll
    for (int off = 1; off < 64; off <<= 1) { s += __shfl_xor(s, off); ss += __shfl_xor(ss, off); }
    float mu = s * (1.f / 384.f);
    float var = ss * (1.f / 384.f) - mu * mu;
    float rstd = rsqrtf(var + 1e-5f);
    const float* zp = zt + (size_t)pix * DIM;
    float* op = yg + (size_t)pix * DIM;
#pragma unroll
    for (int j = 0; j < 6; ++j) {
        int d = lane + (j << 6);
        float zz = zp[d];
        float gate = zz / (1.f + __expf(-zz));
        op[d] = ((v[j] - mu) * rstd * ong[d] + onb[d]) * gate;
    }
}

// ---------------------------------------------------------------------------
extern "C" void kernel_launch(void* const* d_in, const int* in_sizes, int n_in,
                              void* d_out, int out_size, void* d_ws, size_t ws_size,
                              hipStream_t stream)
{
    const float* x    = (const float*)d_in[0];
    const float* c1w  = (const float*)d_in[1];  const float* c1b = (const float*)d_in[2];
    const float* c2w  = (const float*)d_in[3];  const float* c2b = (const float*)d_in[4];
    const float* c3w  = (const float*)d_in[5];  const float* c3b = (const float*)d_in[6];
    const float* c4w  = (const float*)d_in[7];  const float* c4b = (const float*)d_in[8];
    const float* c5w  = (const float*)d_in[9];  const float* c5b = (const float*)d_in[10];
    const float* ln1g = (const float*)d_in[11]; const float* ln1b= (const float*)d_in[12];
    const float* ipw  = (const float*)d_in[13];
    const float* dww  = (const float*)d_in[14]; const float* dwb = (const float*)d_in[15];
    const float* xpw  = (const float*)d_in[16];
    const float* dtw  = (const float*)d_in[17]; const float* dtb = (const float*)d_in[18];
    const float* alog = (const float*)d_in[19]; const float* dsv = (const float*)d_in[20];
    const float* ong  = (const float*)d_in[21]; const float* onb = (const float*)d_in[22];
    const float* opw  = (const float*)d_in[23];
    float* out = (float*)d_out;

    float* ws   = (float*)d_ws;
    float* FN   = ws;                   // (B*L,192) NHWC feature     1,572,864
    float* XN   = FN   + 1572864;       // PART-A / ln-out / CX / PART-C
    float* XP   = XN   + 1572864;       // (B,384,L) planar xp; PA after dw
    float* ZT   = XP   + 3145728;       // (B*L,384) z NHWC
    float* XCNH = ZT   + 3145728;       // (B*L,384) u NHWC; yg in-place
    float* DLT  = XCNH + 3145728;       // (B,L,4,384) delta->y; YN after merge
    float* HF   = DLT  + 12582912;      // carries (bk,c,n,d)         3,145,728
    float* WT14 = HF   + 3145728;       // transformed w c1..c4         129,024
    float* WT5  = WT14 + 129024;        // transformed w c5             110,592
    float* WX   = WT5  + 110592;        // padded x_proj_w (192,384)     73,728
    // total 28,612,096 floats = 109.1 MiB (< 113.5 MiB proven in r2)
    float* PA = XP;                     // 3,145,728 = NB*KD*NC*NST*DIM exactly
    float* CX = XN;                     // 1,572,864 = NB*LEN*192 exactly
    float* PART = XN;                   // conv partials (stage A & C)
    float* YN = DLT;                    // out_proj output NHWC (B*L,192)

    // weight transforms
    k_wtr<<<dim3(72),  256, 0, stream>>>(c1w, WT14,          64, 32, 9 * 64 * 32);
    k_wtr<<<dim3(108), 256, 0, stream>>>(c2w, WT14 + 18432,  96, 32, 9 * 96 * 32);
    k_wtr<<<dim3(144), 256, 0, stream>>>(c3w, WT14 + 46080, 128, 32, 9 * 128 * 32);
    k_wtr<<<dim3(180), 256, 0, stream>>>(c4w, WT14 + 82944, 160, 32, 9 * 160 * 32);
    k_wtr<<<dim3(432), 256, 0, stream>>>(c5w, WT5,          192, 64, 9 * 192 * 64);
    k_wxp<<<dim3(288), 256, 0, stream>>>(xpw, WX);

    // stage A: dense conv block (implicit GEMM, NHWC)
    k_tr_in<<<dim3(HN, NB), 256, 0, stream>>>(x, FN);
    k_convg<0><<<dim3(64, 1, NB * 3), 256, 0, stream>>>(FN, DM, 64, WT14, 32, PART);
    k_ep_nhwc<<<dim3(1024), 256, 0, stream>>>(PART, c1b, FN, 64, 0.01f);
    k_convg<0><<<dim3(64, 1, NB * 3), 256, 0, stream>>>(FN, DM, 96, WT14 + 18432, 32, PART);
    k_ep_nhwc<<<dim3(1024), 256, 0, stream>>>(PART, c2b, FN, 96, 0.01f);
    k_convg<0><<<dim3(64, 1, NB * 3), 256, 0, stream>>>(FN, DM, 128, WT14 + 46080, 32, PART);
    k_ep_nhwc<<<dim3(1024), 256, 0, stream>>>(PART, c3b, FN, 128, 0.01f);
    k_convg<0><<<dim3(64, 1, NB * 3), 256, 0, stream>>>(FN, DM, 160, WT14 + 82944, 32, PART);
    k_ep_nhwc<<<dim3(1024), 256, 0, stream>>>(PART, c4b, FN, 160, 0.01f);

    // stage B: VSS block
    k_ln<<<dim3(NB * LEN / 4), 256, 0, stream>>>(FN, ln1g, ln1b, XN);
    k_gemm<<<dim3(LEN / 64, DIM / 64, NB), 256, 0, stream>>>(XN, DM, ipw, nullptr, XP, DIM, 0);
    k_gemm<<<dim3(LEN / 64, DIM / 64, NB), 256, 0, stream>>>(XN, DM, ipw + (size_t)DIM * DM, nullptr, ZT, DIM, 1);
    k_dw<<<dim3(HN, DIM / 64, NB), 256, 0, stream>>>(XP, dww, dwb, XCNH);
    k_gemm<<<dim3(LEN / 64, 3, NB), 256, 0, stream>>>(XCNH, DIM, WX, nullptr, CX, 192, 1);
    k_delta<<<dim3(LEN / 16, KD, NB), 384, 0, stream>>>(CX, dtw, dtb, DLT);
    k_scan_a<<<dim3(NC, KD, NB), 384, 0, stream>>>(XCNH, CX, alog, DLT, HF, PA);
    k_scan_b<<<dim3(NB * KD * NST * DIM / 256), 256, 0, stream>>>(HF, PA);
    k_scan_c<<<dim3(NC, KD, NB), 384, 0, stream>>>(XCNH, CX, alog, HF, DLT);
    k_merge<<<dim3(NB * LEN / 4), 256, 0, stream>>>(DLT, XCNH, dsv, ong, onb, ZT, XCNH);
    k_gemm<<<dim3(LEN / 64, DM / 64, NB), 256, 0, stream>>>(XCNH, DIM, opw, FN, YN, DM, 1);

    // stage C: final conv (implicit GEMM, planar out)
    k_convg<1><<<dim3(64, 2, NB * 3), 256, 0, stream>>>(YN, DM, 192, WT5, 64, PART);
    k_ep_pl<<<dim3(2048), 256, 0, stream>>>(PART, c5b, out);
}

// Round 10
// 435.448 us; speedup vs baseline: 1.8126x; 1.1093x over previous
//
#include <hip/hip_runtime.h>
#include <hip/hip_bf16.h>
#include <math.h>

// ---- problem constants ----
static constexpr int LEN = 4096;   // H*W
static constexpr int HN  = 64;     // H
static constexpr int WN  = 64;     // W
static constexpr int NB  = 2;      // batch
static constexpr int DM  = 192;    // d_model
static constexpr int DIM = 384;    // d_inner
static constexpr int NST = 16;     // n_state
static constexpr int DTR = 12;     // dt_rank
static constexpr int KD  = 4;      // directions
static constexpr int NC  = 64;     // scan chunks
static constexpr int CHL = LEN / NC; // 64 elements per chunk

// direction k seq-position -> pixel row index (uniform across a wave)
__device__ __forceinline__ int maprow(int k, int gl) {
    int g = (k & 2) ? (LEN - 1 - gl) : gl;
    return (k & 1) ? (((g & 63) << 6) | (g >> 6)) : g;
}

// ---------------------------------------------------------------------------
// weight transform: w (co,ci,3,3) -> wt (t, ci, co)
__global__ void k_wtr(const float* __restrict__ w, float* __restrict__ wt,
                      int cin, int cout, int n)
{
    int idx = blockIdx.x * 256 + threadIdx.x;
    if (idx >= n) return;
    int co = idx % cout; int r = idx / cout;
    int ci = r % cin; int t = r / cin;
    wt[idx] = w[((size_t)(co * cin + ci)) * 9 + t];
}

// pad x_proj_w (4,44,384) -> WX (192,384), rows k*48+c (c<44), zero pad
__global__ void k_wxp(const float* __restrict__ xpw, float* __restrict__ WX)
{
    int idx = blockIdx.x * 256 + threadIdx.x;    // 192*384
    if (idx >= 192 * DIM) return;
    int row = idx / DIM, d = idx - row * DIM;
    int k = row / 48, c = row - k * 48;
    WX[idx] = (c < 44) ? xpw[((size_t)(k * 44 + c)) * DIM + d] : 0.f;
}

// ---------------------------------------------------------------------------
// x (B,64,L) planar -> FN NHWC cols [0,64)
__global__ void k_tr_in(const float* __restrict__ x, float* __restrict__ FN)
{
    __shared__ float t[64][65];
    int b = blockIdx.y, r = blockIdx.x;
    int tid = threadIdx.x;
#pragma unroll
    for (int i = 0; i < 16; ++i) {
        int idx = (i << 8) + tid;
        int c = idx >> 6, xc = idx & 63;
        t[c][xc] = x[((size_t)(b * 64 + c)) * LEN + r * WN + xc];
    }
    __syncthreads();
#pragma unroll
    for (int i = 0; i < 16; ++i) {
        int idx = (i << 8) + tid;
        int px = idx >> 6, c = idx & 63;
        FN[((size_t)(b * LEN + r * WN + px)) * DM + c] = t[c][px];
    }
}

// ---------------------------------------------------------------------------
// implicit-GEMM conv3x3, dy-split partials. tile 64px x 32oc.
// halo-staged: one 66x32 A-tile per ci-chunk serves all 3 dx taps.
template<int PLANAR>
__global__ void __launch_bounds__(256) k_convg(
    const float* __restrict__ in, int cbuf, int cin,
    const float* __restrict__ wt, int wstride,
    float* __restrict__ part)
{
    __shared__ float As[66][36];
    __shared__ float Bs[3][32][33];
    int zz = blockIdx.z;
    int b = zz / 3, s = zz % 3;
    int y0 = blockIdx.x;
    int n0 = blockIdx.y << 5;
    int tid = threadIdx.x;
    int tl = tid & 15, tn = (tid >> 4) << 1;
    int y = y0 + s - 1;
    bool yok = (unsigned)y < (unsigned)HN;
    const float* inb = in + ((size_t)b * LEN + (size_t)y * WN) * cbuf;
    float acc[4][2] = {};

    for (int ci0 = 0; ci0 < cin; ci0 += 32) {
        // stage As[px][ci']: px in [0,66) maps to x = px-1 (halo)
#pragma unroll
        for (int it = 0; it < 3; ++it) {
            int fi = (it << 8) + tid;
            if (fi < 528) {                       // 66 rows x 8 quads
                int px = fi >> 3, ci4 = (fi & 7) << 2;
                int xx = px - 1;
                float4 v = make_float4(0.f, 0.f, 0.f, 0.f);
                if (yok && (unsigned)xx < (unsigned)WN)
                    v = *(const float4*)(inb + (size_t)xx * cbuf + ci0 + ci4);
                *(float4*)(&As[px][ci4]) = v;
            }
        }
        // stage Bs[dx][ci'][oc] for all 3 dx taps
#pragma unroll
        for (int dx = 0; dx < 3; ++dx) {
            int ci = tid >> 3, oc4 = (tid & 7) << 2;
            int t = s * 3 + dx;
            float4 wv = *(const float4*)(wt + (size_t)(t * cin + ci0 + ci) * wstride + n0 + oc4);
            *(float4*)(&Bs[dx][ci][oc4]) = wv;
        }
        __syncthreads();
#pragma unroll
        for (int dx = 0; dx < 3; ++dx) {
#pragma unroll 8
            for (int k = 0; k < 32; ++k) {
                float b0 = Bs[dx][k][tn], b1 = Bs[dx][k][tn + 1];
#pragma unroll
                for (int i = 0; i < 4; ++i) {
                    float a = As[tl + (i << 4) + dx][k];
                    acc[i][0] += a * b0;
                    acc[i][1] += a * b1;
                }
            }
        }
        __syncthreads();
    }
    if (PLANAR) {
#pragma unroll
        for (int j = 0; j < 2; ++j) {
            float* pp = part + ((size_t)((s * NB + b) * 64 + n0 + tn + j)) * LEN + y0 * WN + tl;
#pragma unroll
            for (int i = 0; i < 4; ++i) pp[i << 4] = acc[i][j];
        }
    } else {
#pragma unroll
        for (int i = 0; i < 4; ++i) {
            float* pp = part + (((size_t)(s * NB + b) * LEN) + y0 * WN + tl + (i << 4)) * 32 + tn;
            pp[0] = acc[i][0]; pp[1] = acc[i][1];
        }
    }
}

// epilogue: sum 3 dy-partials + bias + leakyrelu -> FN NHWC col block
__global__ void k_ep_nhwc(const float* __restrict__ part, const float* __restrict__ bias,
                          float* __restrict__ FN, int co0, float slope)
{
    int idx = blockIdx.x * 256 + threadIdx.x;
    int co = idx & 31, px = idx >> 5;
    const size_t S = (size_t)NB * LEN * 32;
    float v = part[idx] + part[S + idx] + part[2 * S + idx] + bias[co];
    v = v > 0.f ? v : v * slope;
    FN[(size_t)px * DM + co0 + co] = v;
}

// epilogue: sum 3 dy-partials + bias -> planar out (B,64,L)
__global__ void k_ep_pl(const float* __restrict__ part, const float* __restrict__ bias,
                        float* __restrict__ out)
{
    int idx = blockIdx.x * 256 + threadIdx.x;
    int oc = (idx >> 12) & 63;
    const size_t S = (size_t)NB * 64 * LEN;
    float v = part[idx] + part[S + idx] + part[2 * S + idx] + bias[oc];
    out[idx] = v;
}

// ---------------------------------------------------------------------------
// LayerNorm over 192 channels, NHWC in/out
__global__ void k_ln(const float* __restrict__ FN, const float* __restrict__ g,
                     const float* __restrict__ be, float* __restrict__ xn)
{
    int lane = threadIdx.x & 63;
    int pix  = (blockIdx.x << 2) + (threadIdx.x >> 6);
    const float* fp = FN + (size_t)pix * DM;
    float v0 = fp[lane];
    float v1 = fp[lane + 64];
    float v2 = fp[lane + 128];
    float s = v0 + v1 + v2, ss = v0 * v0 + v1 * v1 + v2 * v2;
#pragma unroll
    for (int off = 1; off < 64; off <<= 1) { s += __shfl_xor(s, off); ss += __shfl_xor(ss, off); }
    float mu = s * (1.f / 192.f);
    float var = ss * (1.f / 192.f) - mu * mu;
    float rstd = rsqrtf(var + 1e-5f);
    float* op = xn + (size_t)pix * DM;
    op[lane]       = (v0 - mu) * rstd * g[lane]       + be[lane];
    op[lane + 64]  = (v1 - mu) * rstd * g[lane + 64]  + be[lane + 64];
    op[lane + 128] = (v2 - mu) * rstd * g[lane + 128] + be[lane + 128];
}

// ---------------------------------------------------------------------------
// tiled f32 GEMM: A (B*L, K) NHWC x Wt (N, K) -> planar (B,outC,L) or NHWC.
__global__ void __launch_bounds__(256) k_gemm(
    const float* __restrict__ A, int K,
    const float* __restrict__ Wt,
    const float* __restrict__ res,
    float* __restrict__ Cp, int outC, int nhwc)
{
    __shared__ float As[64][65];
    __shared__ float Bs[64][65];
    int b  = blockIdx.z;
    int l0 = blockIdx.x << 6, n0 = blockIdx.y << 6;
    int tid = threadIdx.x;
    int tl = (tid & 15) << 2, tn = (tid >> 4) << 2;
    float acc[4][4] = {};

    for (int k0 = 0; k0 < K; k0 += 64) {
#pragma unroll
        for (int s = 0; s < 4; ++s) {
            int e = (s << 10) + (tid << 2);
            int row = e >> 6, col = e & 63;
            float4 av = *(const float4*)(A + ((size_t)b * LEN + l0 + row) * K + k0 + col);
            As[row][col] = av.x; As[row][col + 1] = av.y; As[row][col + 2] = av.z; As[row][col + 3] = av.w;
            float4 wv = *(const float4*)(Wt + (size_t)(n0 + row) * K + k0 + col);
            Bs[row][col] = wv.x; Bs[row][col + 1] = wv.y; Bs[row][col + 2] = wv.z; Bs[row][col + 3] = wv.w;
        }
        __syncthreads();
#pragma unroll
        for (int kk = 0; kk < 64; ++kk) {
            float a0 = As[tl][kk], a1 = As[tl + 1][kk], a2 = As[tl + 2][kk], a3 = As[tl + 3][kk];
            float b0 = Bs[tn][kk], b1 = Bs[tn + 1][kk], b2 = Bs[tn + 2][kk], b3 = Bs[tn + 3][kk];
            acc[0][0] += a0 * b0; acc[0][1] += a0 * b1; acc[0][2] += a0 * b2; acc[0][3] += a0 * b3;
            acc[1][0] += a1 * b0; acc[1][1] += a1 * b1; acc[1][2] += a1 * b2; acc[1][3] += a1 * b3;
            acc[2][0] += a2 * b0; acc[2][1] += a2 * b1; acc[2][2] += a2 * b2; acc[2][3] += a2 * b3;
            acc[3][0] += a3 * b0; acc[3][1] += a3 * b1; acc[3][2] += a3 * b2; acc[3][3] += a3 * b3;
        }
        __syncthreads();
    }
    if (!nhwc) {
#pragma unroll
        for (int j = 0; j < 4; ++j) {
            size_t o = ((size_t)(b * outC) + n0 + tn + j) * LEN + l0 + tl;
            float4 v;
            v.x = acc[0][j]; v.y = acc[1][j]; v.z = acc[2][j]; v.w = acc[3][j];
            if (res) {
                float4 r = *(const float4*)(res + o);
                v.x += r.x; v.y += r.y; v.z += r.z; v.w += r.w;
            }
            *(float4*)(Cp + o) = v;
        }
    } else {
#pragma unroll
        for (int i = 0; i < 4; ++i) {
            size_t o = ((size_t)b * LEN + l0 + tl + i) * outC + n0 + tn;
            float4 v;
            v.x = acc[i][0]; v.y = acc[i][1]; v.z = acc[i][2]; v.w = acc[i][3];
            if (res) {
                float4 r = *(const float4*)(res + o);
                v.x += r.x; v.y += r.y; v.z += r.z; v.w += r.w;
            }
            *(float4*)(Cp + o) = v;
        }
    }
}

// ---------------------------------------------------------------------------
// depthwise conv3x3 + SiLU : xp planar (B,384,L) -> unh NHWC (B*L, 384)
__global__ void __launch_bounds__(256) k_dw(
    const float* __restrict__ xp, const float* __restrict__ w,
    const float* __restrict__ bias, float* __restrict__ unh)
{
    __shared__ float t[64][65];
    int b = blockIdx.z, cg = blockIdx.y, r = blockIdx.x;
    int x = threadIdx.x & 63, cs = threadIdx.x >> 6;
#pragma unroll
    for (int i = 0; i < 16; ++i) {
        int c = cg * 64 + cs * 16 + i;
        const float* ip = xp + ((size_t)(b * DIM + c)) * LEN;
        const float* wp = w + c * 9;
        float acc = bias[c];
#pragma unroll
        for (int dy = 0; dy < 3; ++dy) {
            int ry = r + dy - 1;
            if ((unsigned)ry >= (unsigned)HN) continue;
#pragma unroll
            for (int dx = 0; dx < 3; ++dx) {
                int xx = x + dx - 1;
                if ((unsigned)xx >= (unsigned)WN) continue;
                acc += ip[ry * WN + xx] * wp[dy * 3 + dx];
            }
        }
        acc = acc / (1.f + __expf(-acc));
        t[x][cs * 16 + i] = acc;
    }
    __syncthreads();
    float* op = unh + ((size_t)b * LEN + r * 64) * DIM + cg * 64;
#pragma unroll
    for (int i = 0; i < 16; ++i) {
        int idx = (i << 8) + threadIdx.x;
        int px = idx >> 6, cc = idx & 63;
        op[(size_t)px * DIM + cc] = t[px][cc];
    }
}

// ---------------------------------------------------------------------------
// delta = softplus(dtb + CX[:, k*48+0..12] @ dtw[k]^T), pixel-order output
__global__ void __launch_bounds__(384) k_delta(
    const float* __restrict__ CX, const float* __restrict__ dtw,
    const float* __restrict__ dtb, float* __restrict__ dlt)
{
    __shared__ float cs[16][12];
    int b = blockIdx.z, k = blockIdx.y;
    int lp0 = blockIdx.x << 4;
    int tid = threadIdx.x;
    if (tid < 192) {
        int p = tid / 12, r = tid - p * 12;
        cs[p][r] = CX[((size_t)(b * LEN) + lp0 + p) * 192 + k * 48 + r];
    }
    __syncthreads();
    float wt[DTR];
    const float* wp = dtw + ((size_t)(k * DIM) + tid) * DTR;
#pragma unroll
    for (int r = 0; r < DTR; ++r) wt[r] = wp[r];
    float bv = dtb[k * DIM + tid];
    float* dbase = dlt + (((size_t)(b * LEN) + lp0) * KD + k) * DIM + tid;
#pragma unroll
    for (int p = 0; p < 16; ++p) {
        float s = bv;
#pragma unroll
        for (int r = 0; r < DTR; ++r) s += cs[p][r] * wt[r];
        s = (s > 20.f) ? s : __logf(1.f + __expf(s));
        dbase[(size_t)p * KD * DIM] = s;
    }
}

// ---------------------------------------------------------------------------
// chunked scan phase A. thread = d; 16 states in registers; B staged from CX.
// geometric-A fast path: A[n]=(n+1)A[0] (true for this model) -> dA[n]=q^(n+1),
// p[n]=p0^(n+1); 1 exp instead of 16. Runtime-verified, exp fallback kept.
__global__ void __launch_bounds__(384) k_scan_a(
    const float* __restrict__ unh, const float* __restrict__ CX,
    const float* __restrict__ alog, const float* __restrict__ dlt,
    float* __restrict__ hf, float* __restrict__ pA)
{
    __shared__ float bs[CHL * 16];
    int b = blockIdx.z, k = blockIdx.y, c = blockIdx.x;
    int d = threadIdx.x;
    for (int i = threadIdx.x; i < CHL * 16; i += 384) {
        int l = i >> 4, n = i & 15;
        int row = maprow(k, c * CHL + l);
        bs[i] = CX[((size_t)(b * LEN) + row) * 192 + k * 48 + 12 + n];
    }
    __syncthreads();

    float A[16], h[16];
    const float* ap = alog + ((size_t)(k * DIM + d)) * NST;
#pragma unroll
    for (int q = 0; q < 4; ++q) {
        float4 av = *(const float4*)(ap + q * 4);
        A[q * 4]     = -__expf(av.x); A[q * 4 + 1] = -__expf(av.y);
        A[q * 4 + 2] = -__expf(av.z); A[q * 4 + 3] = -__expf(av.w);
    }
    bool geo = true;
#pragma unroll
    for (int n = 1; n < 16; ++n)
        geo = geo && (fabsf(A[n] - (n + 1) * A[0]) <= 1e-4f * (n + 1) * fabsf(A[0]));
#pragma unroll
    for (int n = 0; n < 16; ++n) h[n] = 0.f;

    const float* ub = unh + (size_t)b * LEN * DIM + d;
    const float* db = dlt + ((size_t)(b * LEN) * KD + k) * DIM + d;
    size_t base = (((size_t)((b * KD + k) * NC + c)) * NST) * DIM + d;

    float dv0[4], uu0[4], dv1[4], uu1[4];
#pragma unroll
    for (int j = 0; j < 4; ++j) {
        int row = maprow(k, c * CHL + j);
        dv0[j] = db[(size_t)row * KD * DIM];
        uu0[j] = ub[(size_t)row * DIM];
    }
    if (geo) {
        float A0 = A[0];
        float p0 = 1.f;
        for (int l0 = 0; l0 < CHL; l0 += 4) {
            if (l0 + 4 < CHL) {
#pragma unroll
                for (int j = 0; j < 4; ++j) {
                    int row = maprow(k, c * CHL + l0 + 4 + j);
                    dv1[j] = db[(size_t)row * KD * DIM];
                    uu1[j] = ub[(size_t)row * DIM];
                }
            }
#pragma unroll
            for (int j = 0; j < 4; ++j) {
                float du = dv0[j] * uu0[j];
                const float* bl = bs + (l0 + j) * 16;
                float qv = __expf(dv0[j] * A0);
                float pw = qv;
                h[0] = qv * h[0] + du * bl[0];
#pragma unroll
                for (int n = 1; n < 16; ++n) { pw *= qv; h[n] = pw * h[n] + du * bl[n]; }
                p0 *= qv;
            }
#pragma unroll
            for (int j = 0; j < 4; ++j) { dv0[j] = dv1[j]; uu0[j] = uu1[j]; }
        }
        float pw = 1.f;
#pragma unroll
        for (int n = 0; n < 16; ++n) {
            pw *= p0;
            hf[base + (size_t)n * DIM] = h[n];
            pA[base + (size_t)n * DIM] = pw;
        }
    } else {
        float p[16];
#pragma unroll
        for (int n = 0; n < 16; ++n) p[n] = 1.f;
        for (int l0 = 0; l0 < CHL; l0 += 4) {
            if (l0 + 4 < CHL) {
#pragma unroll
                for (int j = 0; j < 4; ++j) {
                    int row = maprow(k, c * CHL + l0 + 4 + j);
                    dv1[j] = db[(size_t)row * KD * DIM];
                    uu1[j] = ub[(size_t)row * DIM];
                }
            }
#pragma unroll
            for (int j = 0; j < 4; ++j) {
                float du = dv0[j] * uu0[j];
                const float* bl = bs + (l0 + j) * 16;
#pragma unroll
                for (int n = 0; n < 16; ++n) {
                    float dA = __expf(dv0[j] * A[n]);
                    h[n] = dA * h[n] + du * bl[n];
                    p[n] *= dA;
                }
            }
#pragma unroll
            for (int j = 0; j < 4; ++j) { dv0[j] = dv1[j]; uu0[j] = uu1[j]; }
        }
#pragma unroll
        for (int n = 0; n < 16; ++n) {
            hf[base + (size_t)n * DIM] = h[n];
            pA[base + (size_t)n * DIM] = p[n];
        }
    }
}

// phase B: serial carry combine over chunks; hf[c] overwritten with carry-IN.
__global__ void k_scan_b(float* __restrict__ hf, const float* __restrict__ pA)
{
    int s = blockIdx.x * 256 + threadIdx.x;          // NB*KD*NST*DIM = 49152
    int bk = s / (NST * DIM);
    int r  = s - bk * (NST * DIM);
    size_t base = (size_t)bk * NC * NST * DIM + r;
    const size_t cs = (size_t)NST * DIM;
    float car = 0.f;
#pragma unroll 8
    for (int c = 0; c < NC; ++c) {
        float hfc = hf[base + c * cs], pc = pA[base + c * cs];
        hf[base + c * cs] = car;
        car = pc * car + hfc;
    }
}

// phase C: re-run chunk from carry-in; geometric-A fast path; y pixel-order.
__global__ void __launch_bounds__(384) k_scan_c(
    const float* __restrict__ unh, const float* __restrict__ CX,
    const float* __restrict__ alog, const float* __restrict__ hf,
    float* __restrict__ dlt)
{
    __shared__ float bs[CHL * 32];
    int b = blockIdx.z, k = blockIdx.y, c = blockIdx.x;
    int d = threadIdx.x;
    for (int i = threadIdx.x; i < CHL * 32; i += 384) {
        int l = i >> 5, n = i & 31;
        int row = maprow(k, c * CHL + l);
        bs[i] = CX[((size_t)(b * LEN) + row) * 192 + k * 48 + 12 + n];
    }
    __syncthreads();

    float A[16], h[16];
    const float* ap = alog + ((size_t)(k * DIM + d)) * NST;
#pragma unroll
    for (int q = 0; q < 4; ++q) {
        float4 av = *(const float4*)(ap + q * 4);
        A[q * 4]     = -__expf(av.x); A[q * 4 + 1] = -__expf(av.y);
        A[q * 4 + 2] = -__expf(av.z); A[q * 4 + 3] = -__expf(av.w);
    }
    bool geo = true;
#pragma unroll
    for (int n = 1; n < 16; ++n)
        geo = geo && (fabsf(A[n] - (n + 1) * A[0]) <= 1e-4f * (n + 1) * fabsf(A[0]));
    size_t base = (((size_t)((b * KD + k) * NC + c)) * NST) * DIM + d;
#pragma unroll
    for (int n = 0; n < 16; ++n) h[n] = hf[base + (size_t)n * DIM];

    const float* ub = unh + (size_t)b * LEN * DIM + d;
    float* db = dlt + ((size_t)(b * LEN) * KD + k) * DIM + d;

    int rows0[4], rows1[4];
    float dv0[4], uu0[4], dv1[4], uu1[4];
#pragma unroll
    for (int j = 0; j < 4; ++j) {
        rows0[j] = maprow(k, c * CHL + j);
        dv0[j] = db[(size_t)rows0[j] * KD * DIM];
        uu0[j] = ub[(size_t)rows0[j] * DIM];
    }
    if (geo) {
        float A0 = A[0];
        for (int l0 = 0; l0 < CHL; l0 += 4) {
            if (l0 + 4 < CHL) {
#pragma unroll
                for (int j = 0; j < 4; ++j) {
                    rows1[j] = maprow(k, c * CHL + l0 + 4 + j);
                    dv1[j] = db[(size_t)rows1[j] * KD * DIM];
                    uu1[j] = ub[(size_t)rows1[j] * DIM];
                }
            }
            float ys[4];
#pragma unroll
            for (int j = 0; j < 4; ++j) {
                const float* bl = bs + (l0 + j) * 32;
                float du = dv0[j] * uu0[j];
                float qv = __expf(dv0[j] * A0);
                float pw = qv;
                h[0] = qv * h[0] + du * bl[0];
                float y = h[0] * bl[16];
#pragma unroll
                for (int n = 1; n < 16; ++n) {
                    pw *= qv;
                    h[n] = pw * h[n] + du * bl[n];
                    y += h[n] * bl[16 + n];
                }
                ys[j] = y;
            }
#pragma unroll
            for (int j = 0; j < 4; ++j) db[(size_t)rows0[j] * KD * DIM] = ys[j];
#pragma unroll
            for (int j = 0; j < 4; ++j) { rows0[j] = rows1[j]; dv0[j] = dv1[j]; uu0[j] = uu1[j]; }
        }
    } else {
        for (int l0 = 0; l0 < CHL; l0 += 4) {
            if (l0 + 4 < CHL) {
#pragma unroll
                for (int j = 0; j < 4; ++j) {
                    rows1[j] = maprow(k, c * CHL + l0 + 4 + j);
                    dv1[j] = db[(size_t)rows1[j] * KD * DIM];
                    uu1[j] = ub[(size_t)rows1[j] * DIM];
                }
            }
            float ys[4];
#pragma unroll
            for (int j = 0; j < 4; ++j) {
                const float* bl = bs + (l0 + j) * 32;
                float du = dv0[j] * uu0[j];
                float y = 0.f;
#pragma unroll
                for (int n = 0; n < 16; ++n) {
                    float dA = __expf(dv0[j] * A[n]);
                    h[n] = dA * h[n] + du * bl[n];
                    y += h[n] * bl[16 + n];
                }
                ys[j] = y;
            }
#pragma unroll
            for (int j = 0; j < 4; ++j) db[(size_t)rows0[j] * KD * DIM] = ys[j];
#pragma unroll
            for (int j = 0; j < 4; ++j) { rows0[j] = rows1[j]; dv0[j] = dv1[j]; uu0[j] = uu1[j]; }
        }
    }
}

// ---------------------------------------------------------------------------
// merge 4 directions + D*u + out-LN + silu(z) gate -> yg NHWC (in-place over unh)
__global__ void k_merge(const float* __restrict__ y4, const float* __restrict__ unh,
                        const float* __restrict__ Ds, const float* __restrict__ ong,
                        const float* __restrict__ onb, const float* __restrict__ zt,
                        float* __restrict__ yg)
{
    int lane = threadIdx.x & 63;
    int pix = (blockIdx.x << 2) + (threadIdx.x >> 6);
    const float* yp = y4 + (size_t)pix * KD * DIM;
    const float* up = unh + (size_t)pix * DIM;
    float v[6]; float s = 0.f, ss = 0.f;
#pragma unroll
    for (int j = 0; j < 6; ++j) {
        int d = lane + (j << 6);
        float y = yp[d] + yp[DIM + d] + yp[2 * DIM + d] + yp[3 * DIM + d];
        float dsum = Ds[d] + Ds[DIM + d] + Ds[2 * DIM + d] + Ds[3 * DIM + d];
        y += dsum * up[d];
        v[j] = y; s += y; ss += y * y;
    }
#pragma unroll
    for (int off = 1; off < 64; off <<= 1) { s += __shfl_xor(s, off); ss += __shfl_xor(ss, off); }
    float mu = s * (1.f / 384.f);
    float var = ss * (1.f / 384.f) - mu * mu;
    float rstd = rsqrtf(var + 1e-5f);
    const float* zp = zt + (size_t)pix * DIM;
    float* op = yg + (size_t)pix * DIM;
#pragma unroll
    for (int j = 0; j < 6; ++j) {
        int d = lane + (j << 6);
        float zz = zp[d];
        float gate = zz / (1.f + __expf(-zz));
        op[d] = ((v[j] - mu) * rstd * ong[d] + onb[d]) * gate;
    }
}

// ---------------------------------------------------------------------------
extern "C" void kernel_launch(void* const* d_in, const int* in_sizes, int n_in,
                              void* d_out, int out_size, void* d_ws, size_t ws_size,
                              hipStream_t stream)
{
    const float* x    = (const float*)d_in[0];
    const float* c1w  = (const float*)d_in[1];  const float* c1b = (const float*)d_in[2];
    const float* c2w  = (const float*)d_in[3];  const float* c2b = (const float*)d_in[4];
    const float* c3w  = (const float*)d_in[5];  const float* c3b = (const float*)d_in[6];
    const float* c4w  = (const float*)d_in[7];  const float* c4b = (const float*)d_in[8];
    const float* c5w  = (const float*)d_in[9];  const float* c5b = (const float*)d_in[10];
    const float* ln1g = (const float*)d_in[11]; const float* ln1b= (const float*)d_in[12];
    const float* ipw  = (const float*)d_in[13];
    const float* dww  = (const float*)d_in[14]; const float* dwb = (const float*)d_in[15];
    const float* xpw  = (const float*)d_in[16];
    const float* dtw  = (const float*)d_in[17]; const float* dtb = (const float*)d_in[18];
    const float* alog = (const float*)d_in[19]; const float* dsv = (const float*)d_in[20];
    const float* ong  = (const float*)d_in[21]; const float* onb = (const float*)d_in[22];
    const float* opw  = (const float*)d_in[23];
    float* out = (float*)d_out;

    float* ws   = (float*)d_ws;
    float* FN   = ws;                   // (B*L,192) NHWC feature     1,572,864
    float* XN   = FN   + 1572864;       // PART-A / ln-out / CX / PART-C
    float* XP   = XN   + 1572864;       // (B,384,L) planar xp; PA after dw
    float* ZT   = XP   + 3145728;       // (B*L,384) z NHWC
    float* XCNH = ZT   + 3145728;       // (B*L,384) u NHWC; yg in-place
    float* DLT  = XCNH + 3145728;       // (B,L,4,384) delta->y; YN after merge
    float* HF   = DLT  + 12582912;      // carries (bk,c,n,d)         3,145,728
    float* WT14 = HF   + 3145728;       // transformed w c1..c4         129,024
    float* WT5  = WT14 + 129024;        // transformed w c5             110,592
    float* WX   = WT5  + 110592;        // padded x_proj_w (192,384)     73,728
    // total 28,612,096 floats = 109.1 MiB
    float* PA = XP;                     // 3,145,728 = NB*KD*NC*NST*DIM exactly
    float* CX = XN;                     // 1,572,864 = NB*LEN*192 exactly
    float* PART = XN;                   // conv partials (stage A & C)
    float* YN = DLT;                    // out_proj output NHWC (B*L,192)

    // weight transforms
    k_wtr<<<dim3(72),  256, 0, stream>>>(c1w, WT14,          64, 32, 9 * 64 * 32);
    k_wtr<<<dim3(108), 256, 0, stream>>>(c2w, WT14 + 18432,  96, 32, 9 * 96 * 32);
    k_wtr<<<dim3(144), 256, 0, stream>>>(c3w, WT14 + 46080, 128, 32, 9 * 128 * 32);
    k_wtr<<<dim3(180), 256, 0, stream>>>(c4w, WT14 + 82944, 160, 32, 9 * 160 * 32);
    k_wtr<<<dim3(432), 256, 0, stream>>>(c5w, WT5,          192, 64, 9 * 192 * 64);
    k_wxp<<<dim3(288), 256, 0, stream>>>(xpw, WX);

    // stage A: dense conv block (implicit GEMM, halo-staged, NHWC)
    k_tr_in<<<dim3(HN, NB), 256, 0, stream>>>(x, FN);
    k_convg<0><<<dim3(64, 1, NB * 3), 256, 0, stream>>>(FN, DM, 64, WT14, 32, PART);
    k_ep_nhwc<<<dim3(1024), 256, 0, stream>>>(PART, c1b, FN, 64, 0.01f);
    k_convg<0><<<dim3(64, 1, NB * 3), 256, 0, stream>>>(FN, DM, 96, WT14 + 18432, 32, PART);
    k_ep_nhwc<<<dim3(1024), 256, 0, stream>>>(PART, c2b, FN, 96, 0.01f);
    k_convg<0><<<dim3(64, 1, NB * 3), 256, 0, stream>>>(FN, DM, 128, WT14 + 46080, 32, PART);
    k_ep_nhwc<<<dim3(1024), 256, 0, stream>>>(PART, c3b, FN, 128, 0.01f);
    k_convg<0><<<dim3(64, 1, NB * 3), 256, 0, stream>>>(FN, DM, 160, WT14 + 82944, 32, PART);
    k_ep_nhwc<<<dim3(1024), 256, 0, stream>>>(PART, c4b, FN, 160, 0.01f);

    // stage B: VSS block
    k_ln<<<dim3(NB * LEN / 4), 256, 0, stream>>>(FN, ln1g, ln1b, XN);
    k_gemm<<<dim3(LEN / 64, DIM / 64, NB), 256, 0, stream>>>(XN, DM, ipw, nullptr, XP, DIM, 0);
    k_gemm<<<dim3(LEN / 64, DIM / 64, NB), 256, 0, stream>>>(XN, DM, ipw + (size_t)DIM * DM, nullptr, ZT, DIM, 1);
    k_dw<<<dim3(HN, DIM / 64, NB), 256, 0, stream>>>(XP, dww, dwb, XCNH);
    k_gemm<<<dim3(LEN / 64, 3, NB), 256, 0, stream>>>(XCNH, DIM, WX, nullptr, CX, 192, 1);
    k_delta<<<dim3(LEN / 16, KD, NB), 384, 0, stream>>>(CX, dtw, dtb, DLT);
    k_scan_a<<<dim3(NC, KD, NB), 384, 0, stream>>>(XCNH, CX, alog, DLT, HF, PA);
    k_scan_b<<<dim3(NB * KD * NST * DIM / 256), 256, 0, stream>>>(HF, PA);
    k_scan_c<<<dim3(NC, KD, NB), 384, 0, stream>>>(XCNH, CX, alog, HF, DLT);
    k_merge<<<dim3(NB * LEN / 4), 256, 0, stream>>>(DLT, XCNH, dsv, ong, onb, ZT, XCNH);
    k_gemm<<<dim3(LEN / 64, DM / 64, NB), 256, 0, stream>>>(XCNH, DIM, opw, FN, YN, DM, 1);

    // stage C: final conv (implicit GEMM, planar out)
    k_convg<1><<<dim3(64, 2, NB * 3), 256, 0, stream>>>(YN, DM, 192, WT5, 64, PART);
    k_ep_pl<<<dim3(2048), 256, 0, stream>>>(PART, c5b, out);
}